// Round 8
// baseline (279.898 us; speedup 1.0000x reference)
//
#include <hip/hip_runtime.h>
#include <math.h>

// ---------- float4 / bf16 / fp8 helpers ----------
typedef float v2f __attribute__((ext_vector_type(2)));
static __device__ __forceinline__ float4 f4s(float v){ return make_float4(v,v,v,v); }
static __device__ __forceinline__ float4 f4add(float4 a, float4 b){ return make_float4(a.x+b.x,a.y+b.y,a.z+b.z,a.w+b.w); }
static __device__ __forceinline__ float4 f4max(float4 a, float4 b){ return make_float4(fmaxf(a.x,b.x),fmaxf(a.y,b.y),fmaxf(a.z,b.z),fmaxf(a.w,b.w)); }
static __device__ __forceinline__ float4 f4scale(float4 a, float s){ return make_float4(a.x*s,a.y*s,a.z*s,a.w*s); }
static __device__ __forceinline__ float4 f4fma(float4 acc, float s, float4 b){
  acc.x += s*b.x; acc.y += s*b.y; acc.z += s*b.z; acc.w += s*b.w; return acc;
}
static __device__ __forceinline__ float4 f4relu(float4 a){ return f4max(a, f4s(0.f)); }
static __device__ __forceinline__ float4 f4leaky(float4 a){
  return make_float4(a.x>0.f?a.x:0.2f*a.x, a.y>0.f?a.y:0.2f*a.y, a.z>0.f?a.z:0.2f*a.z, a.w>0.f?a.w:0.2f*a.w);
}
static __device__ __forceinline__ float4 f4expf(float4 a){ return make_float4(__expf(a.x),__expf(a.y),__expf(a.z),__expf(a.w)); }
static __device__ __forceinline__ unsigned short f2bf(float f){
  unsigned int u = __float_as_uint(f);
  unsigned int r = (u + 0x7fffu + ((u >> 16) & 1u)) >> 16;
  return (unsigned short)r;
}
static __device__ __forceinline__ ushort4 f2bf4(float4 f){
  ushort4 r; r.x=f2bf(f.x); r.y=f2bf(f.y); r.z=f2bf(f.z); r.w=f2bf(f.w); return r;
}
// bf16x4 (as uint2) -> float4 : 4 VALU ops
static __device__ __forceinline__ float4 bfu2f4(uint2 u){
  return make_float4(__uint_as_float(u.x << 16), __uint_as_float(u.x & 0xffff0000u),
                     __uint_as_float(u.y << 16), __uint_as_float(u.y & 0xffff0000u));
}
static __device__ __forceinline__ float4 bfu2f4_lo(uint4 u){ return bfu2f4(make_uint2(u.x, u.y)); }
static __device__ __forceinline__ float4 bfu2f4_hi(uint4 u){ return bfu2f4(make_uint2(u.z, u.w)); }

typedef __attribute__((ext_vector_type(8))) unsigned short u16x8;
static __device__ __forceinline__ u16x8 f2bf8(float4 a, float4 b){
  u16x8 r;
  r[0]=f2bf(a.x); r[1]=f2bf(a.y); r[2]=f2bf(a.z); r[3]=f2bf(a.w);
  r[4]=f2bf(b.x); r[5]=f2bf(b.y); r[6]=f2bf(b.z); r[7]=f2bf(b.w);
  return r;
}
// reduce two float4 across 2 groups at lane stride 8
static __device__ __forceinline__ void red2(float4& a, float4& b){
  a.x += __shfl_xor(a.x, 8); a.y += __shfl_xor(a.y, 8);
  a.z += __shfl_xor(a.z, 8); a.w += __shfl_xor(a.w, 8);
  b.x += __shfl_xor(b.x, 8); b.y += __shfl_xor(b.y, 8);
  b.z += __shfl_xor(b.z, 8); b.w += __shfl_xor(b.w, 8);
}
// fp8 (OCP e4m3) pack/unpack
static __device__ __forceinline__ unsigned char f2fp8(float v){
  return (unsigned char)(__builtin_amdgcn_cvt_pk_fp8_f32(v, v, 0, false) & 0xff);
}
static __device__ __forceinline__ unsigned int f4_fp8x4(float4 v){
  unsigned int r = __builtin_amdgcn_cvt_pk_fp8_f32(v.x, v.y, 0, false);
  r = __builtin_amdgcn_cvt_pk_fp8_f32(v.z, v.w, r, true);
  return r;
}
static __device__ __forceinline__ float4 fp8x4_f4(unsigned int q){
  v2f lo = __builtin_amdgcn_cvt_pk_f32_fp8(q, false);
  v2f hi = __builtin_amdgcn_cvt_pk_f32_fp8(q, true);
  return make_float4(lo[0], lo[1], hi[0], hi[1]);
}
static __device__ __forceinline__ float dot8(float4 a, float4 b, const float* v){
  return a.x*v[0]+a.y*v[1]+a.z*v[2]+a.w*v[3]+b.x*v[4]+b.y*v[5]+b.z*v[6]+b.w*v[7];
}

// ---------- MFMA types ----------
typedef __attribute__((ext_vector_type(8))) short bf16x8;   // 8 bf16 = 4 VGPRs
typedef __attribute__((ext_vector_type(4))) float f32x4;

// ---------- CSR rank + (packed) bf16 weight-fragment table precompute ----------
// blocks [0, fb): rank.  blocks [fb, fb+28): WT fill (7168 slots).
// WT1 = slots [0,2048): W_gat frags (H4 layout, ld 256).
// WT2 = slots [2048,6144): [W_sl|W_sr] frags (ld 64, col split at 64).
// WT3 = slots [6144,7168): [W1top|W1bot] frags (ld 64, col split at 64).
__global__ __launch_bounds__(256) void k_rankw(const int* __restrict__ dst, int* __restrict__ cnt,
                                               int* __restrict__ rank, int E, int fb,
                                               const float* __restrict__ Wg, const float* __restrict__ Wl,
                                               const float* __restrict__ Wr, const float* __restrict__ W1a,
                                               const float* __restrict__ W1b, unsigned short* __restrict__ WT){
  if ((int)blockIdx.x < fb){
    int t = blockIdx.x*256 + threadIdx.x;
    if (t < E) rank[t] = atomicAdd(&cnt[dst[t]], 1);
    return;
  }
  int s = (blockIdx.x - fb)*256 + threadIdx.x;     // 0..7167
  int l = s & 63, f = s >> 6;
  const float* wp; int ld;
  if (s < 2048){
    int cc = f & 15, kb = f >> 4;
    int c  = cc*16 + (l & 15);
    int kr = kb*32 + ((l >> 4) << 3);
    wp = Wg + (size_t)kr*256 + c; ld = 256;
  } else if (s < 6144){
    int f2 = f - 32;
    int cc = f2 & 7, kb = f2 >> 3;
    int c  = cc*16 + (l & 15);
    int kr = kb*32 + ((l >> 4) << 3);
    wp = (c >= 64) ? (Wr + (size_t)kr*64 + (c - 64)) : (Wl + (size_t)kr*64 + c);
    ld = 64;
  } else {
    int f3 = f - 96;
    int cc = f3 & 7, kb = f3 >> 3;
    int c  = cc*16 + (l & 15);
    int kr = kb*32 + ((l >> 4) << 3);
    wp = (c >= 64) ? (W1b + (size_t)kr*64 + (c - 64)) : (W1a + (size_t)kr*64 + c);
    ld = 64;
  }
  u16x8 o;
  #pragma unroll
  for (int j = 0; j < 8; ++j) o[j] = f2bf(wp[(size_t)j*ld]);
  *(u16x8*)(WT + (size_t)s*8) = o;
}

// scan1 (blocks [0,nb)) + GAT attention basis vectors Vs/Vd (block nb, independent work packed in)
__global__ __launch_bounds__(256) void k_scan1v(const int* __restrict__ cnt, int* __restrict__ excl,
                                                int* __restrict__ bsum, int n, int nb,
                                                const float* __restrict__ Wg, const float* __restrict__ as,
                                                const float* __restrict__ ad, float* __restrict__ Vs,
                                                float* __restrict__ Vd){
  if ((int)blockIdx.x == nb){
    int t = threadIdx.x;
    int h = t >> 6, k = t & 63;
    float s = 0.f, d = 0.f;
    const float* wr = Wg + (size_t)k*256 + h*64;
    const float* ar = as + h*64;
    const float* dr = ad + h*64;
    for (int c = 0; c < 64; ++c){ float w = wr[c]; s += w*ar[c]; d += w*dr[c]; }
    Vs[t] = s; Vd[t] = d;
    return;
  }
  __shared__ int sc[256];
  int t = threadIdx.x; int i = blockIdx.x*256 + t;
  int v = (i<n)?cnt[i]:0;
  sc[t]=v; __syncthreads();
  for (int o=1;o<256;o<<=1){ int a=(t>=o)?sc[t-o]:0; __syncthreads(); sc[t]+=a; __syncthreads(); }
  if (i<n) excl[i] = sc[t]-v;
  if (t==255) bsum[blockIdx.x] = sc[t];
}
// scan3 with per-block redundant in-LDS scan of bsum
__global__ __launch_bounds__(256) void k_scan3b(const int* __restrict__ cnt, const int* __restrict__ excl,
                                                const int* __restrict__ bsum, int* __restrict__ offs,
                                                float* __restrict__ dinv, int n, int E, int nb){
  __shared__ int sb[256];
  int t = threadIdx.x;
  int v = (t<nb)?bsum[t]:0;
  sb[t]=v; __syncthreads();
  for (int o=1;o<256;o<<=1){ int a=(t>=o)?sb[t-o]:0; __syncthreads(); sb[t]+=a; __syncthreads(); }
  int bex = sb[blockIdx.x] - bsum[blockIdx.x];     // exclusive prefix for this block
  int i = blockIdx.x*256 + t;
  if (i < n){
    offs[i] = excl[i] + bex;
    dinv[i] = rsqrtf((float)cnt[i] + 1.0f);   // deg includes self-loop
    if (i == 0) offs[n] = E;
  }
}

// ---------- fused CSR-fill + GCN GEMM (independent work, one dispatch) ----------
// blocks [0, fb): csr scatter-fill.  blocks [fb, fb+gtiles): A8 = fp8(dinv * (x @ W_gcn)).
__global__ __launch_bounds__(256) void k_fillg(const int* __restrict__ src, const int* __restrict__ dstv,
                                               const int* __restrict__ offs, const int* __restrict__ rank,
                                               int* __restrict__ csr, int E, int fb,
                                               const float* __restrict__ x, const float* __restrict__ Wg,
                                               unsigned char* __restrict__ a8, int n,
                                               const float* __restrict__ dinv){
  if ((int)blockIdx.x < fb){
    int t = blockIdx.x*256 + threadIdx.x;
    if (t < E) csr[offs[dstv[t]] + rank[t]] = src[t];
    return;
  }
  // ---- GCN GEMM: K=128 (KB=4), Cout=64 (CC=4), f32 in, fp8 out, rowscale=dinv ----
  __shared__ unsigned short wb[1024*8];        // 16 KB weight frags
  int tid = threadIdx.x;
  for (int s = tid; s < 1024; s += 256){
    int l = s & 63, f = s >> 6;
    int cc = f & 3, kb = f >> 2;
    int c  = cc*16 + (l & 15);
    int kr = kb*32 + ((l >> 4) << 3);
    const float* wp = Wg + (size_t)kr*64 + c;
    unsigned short* dp = &wb[s*8];
    #pragma unroll
    for (int j = 0; j < 8; ++j) dp[j] = f2bf(wp[(size_t)j*64]);
  }
  __syncthreads();
  int wv = tid >> 6, l = tid & 63;
  int lrow = l & 15;
  int lk = (l >> 4) << 3;
  int g = blockIdx.x - fb;                     // exactly one 64-row group per block
  int r0 = (g << 6) + (wv << 4);
  int m = r0 + lrow;
  bf16x8 afr[4];
  #pragma unroll
  for (int kb = 0; kb < 4; ++kb){
    bf16x8 a = {0,0,0,0,0,0,0,0};
    if (m < n){
      const float* p = x + (size_t)m*128 + kb*32 + lk;
      float4 f0 = *(const float4*)p;
      float4 f1 = *(const float4*)(p + 4);
      a[0]=(short)f2bf(f0.x); a[1]=(short)f2bf(f0.y); a[2]=(short)f2bf(f0.z); a[3]=(short)f2bf(f0.w);
      a[4]=(short)f2bf(f1.x); a[5]=(short)f2bf(f1.y); a[6]=(short)f2bf(f1.z); a[7]=(short)f2bf(f1.w);
    }
    afr[kb] = a;
  }
  int rbase = r0 + ((l >> 4) << 2);
  float sc[4];
  #pragma unroll
  for (int r = 0; r < 4; ++r) sc[r] = (rbase + r < n) ? dinv[rbase + r] : 0.f;
  #pragma unroll
  for (int cc = 0; cc < 4; ++cc){
    f32x4 acc = {0.f, 0.f, 0.f, 0.f};
    #pragma unroll
    for (int kb = 0; kb < 4; ++kb){
      bf16x8 b = *(const bf16x8*)&wb[((kb*4 + cc)*64 + l)*8];
      acc = __builtin_amdgcn_mfma_f32_16x16x32_bf16(afr[kb], b, acc, 0, 0, 0);
    }
    int c = cc*16 + lrow;
    #pragma unroll
    for (int r = 0; r < 4; ++r){
      int rr = rbase + r;
      if (rr < n) a8[(size_t)rr*64 + c] = f2fp8(acc[r] * sc[r]);
    }
  }
}

// ---------- GCN aggregation + fused GAT-logit epilogue ----------
__global__ __launch_bounds__(256) void k_gcn(const unsigned char* __restrict__ a8, const float* __restrict__ dinv,
                                             const float* __restrict__ b, const int* __restrict__ offs,
                                             const int* __restrict__ csr, const float* __restrict__ Vs,
                                             const float* __restrict__ Vd, unsigned char* __restrict__ h8,
                                             float* __restrict__ D, int n){
  __shared__ float svs[256], svd[256];
  svs[threadIdx.x] = Vs[threadIdx.x];
  svd[threadIdx.x] = Vd[threadIdx.x];
  __syncthreads();
  int l = threadIdx.x & 63;
  int node = (((blockIdx.x*256 + threadIdx.x) >> 6) << 2) + (l >> 4);
  int l15 = l & 15;
  int grp = l15 >> 3, sub = l15 & 7;
  bool ok = node < n;
  int beg = 0, end = 0;
  float di = 0.f;
  if (ok){ beg = offs[node]; end = offs[node+1]; di = dinv[node]; }
  float4 aL0 = f4s(0.f), aH0 = f4s(0.f), aL1 = f4s(0.f), aH1 = f4s(0.f);
  int i = beg + grp;
  for (; i + 2 < end; i += 4){
    int s0 = csr[i], s1 = csr[i+2];
    uint2 u0 = *(const uint2*)(a8 + (size_t)s0*64 + (sub<<3));
    uint2 u1 = *(const uint2*)(a8 + (size_t)s1*64 + (sub<<3));
    aL0 = f4add(aL0, fp8x4_f4(u0.x)); aH0 = f4add(aH0, fp8x4_f4(u0.y));
    aL1 = f4add(aL1, fp8x4_f4(u1.x)); aH1 = f4add(aH1, fp8x4_f4(u1.y));
  }
  if (i < end){
    int s0 = csr[i];
    uint2 u0 = *(const uint2*)(a8 + (size_t)s0*64 + (sub<<3));
    aL0 = f4add(aL0, fp8x4_f4(u0.x)); aH0 = f4add(aH0, fp8x4_f4(u0.y));
  }
  float4 aL = f4add(aL0, aL1), aH = f4add(aH0, aH1);
  red2(aL, aH);
  if (ok){
    uint2 us = *(const uint2*)(a8 + (size_t)node*64 + (sub<<3));   // self (pre-scaled)
    aL = f4add(aL, fp8x4_f4(us.x)); aH = f4add(aH, fp8x4_f4(us.y));
    float4 b0 = *(const float4*)(b + (sub<<3));
    float4 b1 = *(const float4*)(b + (sub<<3) + 4);
    float4 r0 = f4relu(f4fma(b0, di, aL));                          // both groups compute H slice
    float4 r1 = f4relu(f4fma(b1, di, aH));
    if (grp == 0){
      uint2 q; q.x = f4_fp8x4(r0); q.y = f4_fp8x4(r1);
      *(uint2*)(h8 + (size_t)node*64 + (sub<<3)) = q;
    }
    // GAT logits: this group's two heads
    const float* vs0 = svs + (grp*128) + (sub<<3);   // head grp*2   (h*64 stride)
    const float* vd0 = svd + (grp*128) + (sub<<3);
    float s0 = dot8(r0, r1, vs0);
    float s1 = dot8(r0, r1, vs0 + 64);
    float d0 = dot8(r0, r1, vd0);
    float d1 = dot8(r0, r1, vd0 + 64);
    #pragma unroll
    for (int o = 1; o < 8; o <<= 1){                 // 8-lane cluster reduce (ok uniform per cluster)
      s0 += __shfl_xor(s0, o); s1 += __shfl_xor(s1, o);
      d0 += __shfl_xor(d0, o); d1 += __shfl_xor(d1, o);
    }
    if (sub == 0){
      *(float2*)(D + (size_t)node*8 + grp*2)     = make_float2(s0, s1);
      *(float2*)(D + (size_t)node*8 + 4 + grp*2) = make_float2(d0, d1);
    }
  }
}

// ---------- fused GAT softmax + aggregation + GAT-GEMM + SAGE-GEMM (32 nodes/block) ----------
// Softmax: 4 sequential batches of 8 nodes; per-edge exp weights RECOMPUTED from L2-resident D
// in phase C (bit-identical, kills the 16 KB wl cache).  GEMM: stage-A writes G IN-PLACE over
// ytile (wave-private column stripe; A-frags register-held first), stage-B = ytile@[Wl|Wr].
// LDS = sl 4 KB + ytile 16.5 KB -> 7 blocks/CU (28 waves).
#define GAT_CAP 128
__global__ __launch_bounds__(256) void k_gat2f(const float* __restrict__ D, const unsigned char* __restrict__ H8,
                                               const int* __restrict__ offs, const int* __restrict__ csr,
                                               const unsigned short* __restrict__ WT, const float* __restrict__ bg,
                                               unsigned short* __restrict__ R, unsigned char* __restrict__ P8, int n){
  __shared__ int sl[8][GAT_CAP];                // 4 KB (src byte-offsets)
  __shared__ unsigned short ytile[32][264];     // 16.5 KB (Y, then G in-place)
  const unsigned short* WT1 = WT;               // 2048 slots (W_gat frags)
  const unsigned short* WT2 = WT + 2048*8;      // 4096 slots ([Wl|Wr] frags)
  int tid = threadIdx.x;
  int hw = tid >> 5;                 // half-wave index in block (0..7)
  int l5 = tid & 31;
  int grp = l5 >> 4;
  int sub = l5 & 15;
  // ---- softmax + aggregation: 4 batches of 8 nodes ----
  for (int batch = 0; batch < 4; ++batch){
    int lrow32 = batch*8 + hw;                  // ytile row
    int node = blockIdx.x*32 + lrow32;
    if (node < n){
      int beg = offs[node], end = offs[node+1];
      int deg = end - beg;
      float4 ed  = *(const float4*)(D + (size_t)node*8 + 4);
      float4 es0 = *(const float4*)(D + (size_t)node*8);
      float4 wself = f4expf(f4leaky(f4add(es0, ed)));
      // phase A: src byte-offsets -> LDS (first GAT_CAP), z accumulation (all edges)
      float4 z4 = f4s(0.f);
      for (int i = beg + l5; i < end; i += 32){
        int s = csr[i];
        float4 w = f4expf(f4leaky(f4add(*(const float4*)(D + (size_t)s*8), ed)));
        int li = i - beg;
        if (li < GAT_CAP) sl[hw][li] = s << 6;      // 64 B per H8 row
        z4 = f4add(z4, w);
      }
      for (int m = 1; m < 32; m <<= 1){
        z4.x += __shfl_xor(z4.x, m); z4.y += __shfl_xor(z4.y, m);
        z4.z += __shfl_xor(z4.z, m); z4.w += __shfl_xor(z4.w, m);
      }
      z4 = f4add(z4, wself);
      // phase C: 2 edge-groups x 16 lanes per node; w recomputed from D (bit-identical)
      int c0b = sub << 2;           // byte offset of 4-col fp8 slice
      float4 a0 = f4s(0.f), a1 = f4s(0.f), a2 = f4s(0.f), a3 = f4s(0.f);  // per-head accumulators
      int nl = deg < GAT_CAP ? deg : GAT_CAP;
      int i = grp;
      for (; i + 2 < nl; i += 4){
        int o0 = sl[hw][i], o1 = sl[hw][i+2];
        float4 e0 = *(const float4*)(D + ((size_t)(o0 >> 6))*8);
        float4 e1 = *(const float4*)(D + ((size_t)(o1 >> 6))*8);
        unsigned int q0 = *(const unsigned int*)(H8 + o0 + c0b);
        unsigned int q1 = *(const unsigned int*)(H8 + o1 + c0b);
        float4 w0 = f4expf(f4leaky(f4add(e0, ed)));
        float4 w1 = f4expf(f4leaky(f4add(e1, ed)));
        float4 f0 = fp8x4_f4(q0);
        float4 f1 = fp8x4_f4(q1);
        a0 = f4fma(a0, w0.x, f0); a1 = f4fma(a1, w0.y, f0);
        a2 = f4fma(a2, w0.z, f0); a3 = f4fma(a3, w0.w, f0);
        a0 = f4fma(a0, w1.x, f1); a1 = f4fma(a1, w1.y, f1);
        a2 = f4fma(a2, w1.z, f1); a3 = f4fma(a3, w1.w, f1);
      }
      if (i < nl){
        int o0 = sl[hw][i];
        float4 e0 = *(const float4*)(D + ((size_t)(o0 >> 6))*8);
        unsigned int q0 = *(const unsigned int*)(H8 + o0 + c0b);
        float4 w0 = f4expf(f4leaky(f4add(e0, ed)));
        float4 f0 = fp8x4_f4(q0);
        a0 = f4fma(a0, w0.x, f0); a1 = f4fma(a1, w0.y, f0);
        a2 = f4fma(a2, w0.z, f0); a3 = f4fma(a3, w0.w, f0);
      }
      for (int j = nl + grp; j < deg; j += 2){   // LDS overflow fallback (essentially never)
        int s = csr[beg+j];
        float4 e = f4leaky(f4add(*(const float4*)(D + (size_t)s*8), ed));
        float4 w = f4expf(e);
        float4 f0 = fp8x4_f4(*(const unsigned int*)(H8 + ((size_t)s << 6) + c0b));
        a0 = f4fma(a0, w.x, f0); a1 = f4fma(a1, w.y, f0);
        a2 = f4fma(a2, w.z, f0); a3 = f4fma(a3, w.w, f0);
      }
      // cross-group reduce (lane stride 16, stays within half-wave)
      a0.x += __shfl_xor(a0.x, 16); a0.y += __shfl_xor(a0.y, 16); a0.z += __shfl_xor(a0.z, 16); a0.w += __shfl_xor(a0.w, 16);
      a1.x += __shfl_xor(a1.x, 16); a1.y += __shfl_xor(a1.y, 16); a1.z += __shfl_xor(a1.z, 16); a1.w += __shfl_xor(a1.w, 16);
      a2.x += __shfl_xor(a2.x, 16); a2.y += __shfl_xor(a2.y, 16); a2.z += __shfl_xor(a2.z, 16); a2.w += __shfl_xor(a2.w, 16);
      a3.x += __shfl_xor(a3.x, 16); a3.y += __shfl_xor(a3.y, 16); a3.z += __shfl_xor(a3.z, 16); a3.w += __shfl_xor(a3.w, 16);
      if (grp == 0){
        float4 fs = fp8x4_f4(*(const unsigned int*)(H8 + ((size_t)node << 6) + c0b));   // self term
        a0 = f4fma(a0, wself.x, fs);
        a1 = f4fma(a1, wself.y, fs);
        a2 = f4fma(a2, wself.z, fs);
        a3 = f4fma(a3, wself.w, fs);
        a0 = f4scale(a0, 1.f/(z4.x + 1e-16f));
        a1 = f4scale(a1, 1.f/(z4.y + 1e-16f));
        a2 = f4scale(a2, 1.f/(z4.z + 1e-16f));
        a3 = f4scale(a3, 1.f/(z4.w + 1e-16f));
        // Y row -> LDS (head-major, bf16, same rounding as before)
        unsigned short* yp = &ytile[lrow32][sub << 2];
        *(ushort4*)(yp)       = f2bf4(a0);
        *(ushort4*)(yp + 64)  = f2bf4(a1);
        *(ushort4*)(yp + 128) = f2bf4(a2);
        *(ushort4*)(yp + 192) = f2bf4(a3);
      }
    } else if (grp == 0){
      ushort4 z = make_ushort4(0,0,0,0);
      unsigned short* yp = &ytile[lrow32][sub << 2];
      *(ushort4*)(yp)       = z;
      *(ushort4*)(yp + 64)  = z;
      *(ushort4*)(yp + 128) = z;
      *(ushort4*)(yp + 192) = z;
    }
  }
  __syncthreads();      // ytile complete
  // ---- GEMM phase over this block's 32 node-rows (two full 16-row MFMA tiles) ----
  int wv = tid >> 6, l = tid & 63;
  int lrow = l & 15;
  int lk = (l >> 4) << 3;
  int rbase4 = (l >> 4) << 2;         // 0,4,8,12
  // stage-A: G = relu(ytile@Wg + bg) written IN-PLACE over ytile.
  // Wave wv reads & writes ONLY column stripe [wv*64, wv*64+64) (head wv) -> wave-private;
  // A-frags are loaded into registers before any write (in-wave anti-dep satisfied).
  bf16x8 afA[2][2];                   // [tile][kb]
  #pragma unroll
  for (int t = 0; t < 2; ++t){
    afA[t][0] = *(const bf16x8*)&ytile[t*16 + lrow][wv*64 + lk];
    afA[t][1] = *(const bf16x8*)&ytile[t*16 + lrow][wv*64 + 32 + lk];
  }
  #pragma unroll
  for (int q = 0; q < 4; ++q){
    int cc = wv*4 + q;
    bf16x8 b0 = *(const bf16x8*)&WT1[((size_t)((0*16 + cc)*64 + l))*8];
    bf16x8 b1 = *(const bf16x8*)&WT1[((size_t)((1*16 + cc)*64 + l))*8];
    int c = cc*16 + lrow;
    float bv = bg[c];
    #pragma unroll
    for (int t = 0; t < 2; ++t){
      f32x4 acc = {0.f, 0.f, 0.f, 0.f};
      acc = __builtin_amdgcn_mfma_f32_16x16x32_bf16(afA[t][0], b0, acc, 0, 0, 0);
      acc = __builtin_amdgcn_mfma_f32_16x16x32_bf16(afA[t][1], b1, acc, 0, 0, 0);
      #pragma unroll
      for (int r = 0; r < 4; ++r)
        ytile[t*16 + rbase4 + r][c] = f2bf(fmaxf(acc[r] + bv, 0.f));
    }
  }
  __syncthreads();      // G complete (cross-wave columns)
  // stage-B: [P8|R] = G @ [Wl|Wr]; wave wv owns cc = wv*2, wv*2+1; B-frags shared across tiles
  bf16x8 afb[2][8];
  #pragma unroll
  for (int t = 0; t < 2; ++t)
    #pragma unroll
    for (int kb = 0; kb < 8; ++kb)
      afb[t][kb] = *(const bf16x8*)&ytile[t*16 + lrow][kb*32 + lk];
  #pragma unroll
  for (int q = 0; q < 2; ++q){
    int cc = wv*2 + q;
    f32x4 acc0 = {0.f, 0.f, 0.f, 0.f};
    f32x4 acc1 = {0.f, 0.f, 0.f, 0.f};
    #pragma unroll
    for (int kb = 0; kb < 8; ++kb){
      bf16x8 b = *(const bf16x8*)&WT2[((size_t)((kb*8 + cc)*64 + l))*8];
      acc0 = __builtin_amdgcn_mfma_f32_16x16x32_bf16(afb[0][kb], b, acc0, 0, 0, 0);
      acc1 = __builtin_amdgcn_mfma_f32_16x16x32_bf16(afb[1][kb], b, acc1, 0, 0, 0);
    }
    int c = cc*16 + lrow;
    #pragma unroll
    for (int t = 0; t < 2; ++t){
      const f32x4& acc = t ? acc1 : acc0;
      #pragma unroll
      for (int r = 0; r < 4; ++r){
        int nd = blockIdx.x*32 + t*16 + rbase4 + r;
        if (nd < n){
          float v = acc[r];
          if (c < 64) P8[(size_t)nd*64 + c] = f2fp8(v);
          else        R[(size_t)nd*64 + (c - 64)] = f2bf(v);
        }
      }
    }
  }
}

// ---------- SAGE aggregation + fused edge-MLP GEMM epilogue ----------
// W1 frags now read from precomputed L2-resident WT3 (no per-block staging, LDS = 2.3 KB).
__global__ __launch_bounds__(256) void k_sage(const unsigned char* __restrict__ P8, const unsigned short* __restrict__ R,
                                              const float* __restrict__ b, const int* __restrict__ offs,
                                              const int* __restrict__ csr, const unsigned short* __restrict__ WT3,
                                              unsigned char* __restrict__ T2, int n){
  __shared__ unsigned short stile[16][72];     // 16 S rows bf16, pad 72 (144 B stride)
  int tid = threadIdx.x;
  int wv = tid >> 6, l = tid & 63;
  int base = blockIdx.x*16;
  int lrow16 = (wv << 2) + (l >> 4);           // block-local row 0..15
  int node = base + lrow16;
  int l15 = l & 15;
  int grp = l15 >> 3, sub = l15 & 7;
  bool ok = node < n;
  int beg = 0, end = 0;
  if (ok){ beg = offs[node]; end = offs[node+1]; }
  float4 aL0 = f4s(0.f), aH0 = f4s(0.f), aL1 = f4s(0.f), aH1 = f4s(0.f);
  int i = beg + grp;
  for (; i + 2 < end; i += 4){
    int s0 = csr[i], s1 = csr[i+2];
    uint2 u0 = *(const uint2*)(P8 + (size_t)s0*64 + (sub<<3));
    uint2 u1 = *(const uint2*)(P8 + (size_t)s1*64 + (sub<<3));
    aL0 = f4add(aL0, fp8x4_f4(u0.x)); aH0 = f4add(aH0, fp8x4_f4(u0.y));
    aL1 = f4add(aL1, fp8x4_f4(u1.x)); aH1 = f4add(aH1, fp8x4_f4(u1.y));
  }
  if (i < end){
    int s0 = csr[i];
    uint2 u0 = *(const uint2*)(P8 + (size_t)s0*64 + (sub<<3));
    aL0 = f4add(aL0, fp8x4_f4(u0.x)); aH0 = f4add(aH0, fp8x4_f4(u0.y));
  }
  float4 aL = f4add(aL0, aL1), aH = f4add(aH0, aH1);
  red2(aL, aH);
  float4 r0 = f4s(0.f), r1 = f4s(0.f);
  if (ok){
    float minv = 1.f / fmaxf((float)(end - beg), 1.f);
    uint4 ur = *(const uint4*)(R + (size_t)node*64 + (sub<<3));
    float4 b0 = *(const float4*)(b + (sub<<3));
    float4 b1 = *(const float4*)(b + (sub<<3) + 4);
    r0 = f4relu(f4add(f4fma(b0, minv, aL), bfu2f4_lo(ur)));
    r1 = f4relu(f4add(f4fma(b1, minv, aH), bfu2f4_hi(ur)));
  }
  if (grp == 0) *(u16x8*)&stile[lrow16][sub << 3] = f2bf8(r0, r1);
  __syncthreads();
  // MFMA epilogue: 16 rows x 128 cols, K=64; waves split the 8 col-chunks (2 each)
  int lrow = l & 15, lk = (l >> 4) << 3;
  bf16x8 af0 = *(const bf16x8*)&stile[lrow][lk];
  bf16x8 af1 = *(const bf16x8*)&stile[lrow][32 + lk];
  int rbase = (l >> 4) << 2;
  #pragma unroll
  for (int q = 0; q < 2; ++q){
    int cc = wv*2 + q;
    f32x4 acc = {0.f, 0.f, 0.f, 0.f};
    acc = __builtin_amdgcn_mfma_f32_16x16x32_bf16(af0, *(const bf16x8*)&WT3[((size_t)((0*8 + cc)*64 + l))*8], acc, 0, 0, 0);
    acc = __builtin_amdgcn_mfma_f32_16x16x32_bf16(af1, *(const bf16x8*)&WT3[((size_t)((1*8 + cc)*64 + l))*8], acc, 0, 0, 0);
    int c = cc*16 + lrow;
    #pragma unroll
    for (int r = 0; r < 4; ++r){
      int nd = base + rbase + r;
      if (nd < n) T2[(size_t)nd*128 + c] = f2fp8(acc[r]);
    }
  }
}

// ---------- edge MLP, edge-order: 8 lanes/edge; T2 = [U|V] fp8 rows of 128 B ----------
__global__ __launch_bounds__(256) void k_mlp(const unsigned char* __restrict__ T2,
                                             const float* __restrict__ b1, const float* __restrict__ W2,
                                             const float* __restrict__ b2, const int* __restrict__ src,
                                             const int* __restrict__ dst, float* __restrict__ out, int E){
  int t = threadIdx.x;
  int e = blockIdx.x*32 + (t >> 3);
  if (e >= E) return;
  int sub = t & 7;
  int s = src[e], d = dst[e];
  uint2 uu = *(const uint2*)(T2 + (size_t)s*128 + (sub<<3));        // 8 fp8 of U[s]
  uint2 vv = *(const uint2*)(T2 + (size_t)d*128 + 64 + (sub<<3));   // 8 fp8 of V[d]
  float4 u0 = fp8x4_f4(uu.x), u1 = fp8x4_f4(uu.y);
  float4 v0 = fp8x4_f4(vv.x), v1 = fp8x4_f4(vv.y);
  float4 bb0 = *(const float4*)(b1 + (sub<<3));
  float4 bb1 = *(const float4*)(b1 + (sub<<3) + 4);
  float4 w0 = *(const float4*)(W2 + (sub<<3));
  float4 w1 = *(const float4*)(W2 + (sub<<3) + 4);
  float4 ta = f4relu(f4add(f4add(u0, v0), bb0));
  float4 tb = f4relu(f4add(f4add(u1, v1), bb1));
  float p = ta.x*w0.x + ta.y*w0.y + ta.z*w0.z + ta.w*w0.w
          + tb.x*w1.x + tb.y*w1.y + tb.z*w1.z + tb.w*w1.w;
  p += __shfl_xor(p, 1);
  p += __shfl_xor(p, 2);
  p += __shfl_xor(p, 4);
  if (sub == 0) out[e] = 1.f / (1.f + __expf(-(p + b2[0])));
}

extern "C" void kernel_launch(void* const* d_in, const int* in_sizes, int n_in,
                              void* d_out, int out_size, void* d_ws, size_t ws_size,
                              hipStream_t stream){
  const float* x     = (const float*)d_in[0];
  const int*   eidx  = (const int*)  d_in[1];
  const float* W_gcn = (const float*)d_in[2];
  const float* b_gcn = (const float*)d_in[3];
  const float* W_gat = (const float*)d_in[4];
  const float* att_s = (const float*)d_in[5];
  const float* att_d = (const float*)d_in[6];
  const float* b_gat = (const float*)d_in[7];
  const float* W_sl  = (const float*)d_in[8];
  const float* b_sg  = (const float*)d_in[9];
  const float* W_sr  = (const float*)d_in[10];
  const float* W1    = (const float*)d_in[11];
  const float* b1    = (const float*)d_in[12];
  const float* W2    = (const float*)d_in[13];
  const float* b2    = (const float*)d_in[14];
  float* out = (float*)d_out;

  const int N = in_sizes[0] / 128;
  const int E = in_sizes[1] / 2;
  const int* src = eidx;
  const int* dst = eidx + E;

  // ---- workspace layout: f32, then bf16, then fp8, then int ----
  float* ws   = (float*)d_ws;
  float* dinv = ws;                        // N
  float* D    = dinv + (size_t)N;          // N*8  (a_s | a_d)
  float* Vs   = D + (size_t)N*8;           // 256
  float* Vd   = Vs + 256;                  // 256
  unsigned short* WT = (unsigned short*)(Vd + 256);        // 7168*8 bf16 weight frag tables (112 KB)
  unsigned short* R  = WT + (size_t)7168*8;// N*64  bf16 (SAGE root term, compact)
  unsigned char*  A8 = (unsigned char*)(R + (size_t)N*64); // N*64  fp8 (dinv * x @ W_gcn)
  unsigned char*  H8 = A8 + (size_t)N*64;  // N*64  fp8 (GCN out shadow)
  unsigned char*  P8 = H8 + (size_t)N*64;  // N*64  fp8 (SAGE neighbor term, compact)
  unsigned char*  T2 = P8 + (size_t)N*64;  // N*128 fp8 (U | V)
  int* cnt  = (int*)(T2 + (size_t)N*128);  // N
  int* excl = cnt + N;                     // N
  int* bsum = excl + N;                    // 256
  int* offs = bsum + 256;                  // N+1
  int* rank = offs + N + 1;                // E
  int* csr  = rank + E;                    // E

  const int nb = (N + 255) / 256;
  const int fb = (E + 255) / 256;
  const int gtiles = (N + 63) / 64;
  const int nwb = (N + 15) / 16;          // 4 nodes/wave kernels (16 nodes/block)

  // ---- CSR build (+ packed independent work: WT frag tables, Vs/Vd basis, GCN GEMM) ----
  hipMemsetAsync(cnt, 0, (size_t)N*sizeof(int), stream);
  k_rankw <<<fb + 28, 256, 0, stream>>>(dst, cnt, rank, E, fb, W_gat, W_sl, W_sr,
                                        W1, W1 + 64*64, WT);
  k_scan1v<<<nb + 1, 256, 0, stream>>>(cnt, excl, bsum, N, nb, W_gat, att_s, att_d, Vs, Vd);
  k_scan3b<<<nb, 256, 0, stream>>>(cnt, excl, bsum, offs, dinv, N, E, nb);
  k_fillg <<<fb + gtiles, 256, 0, stream>>>(src, dst, offs, rank, csr, E, fb,
                                            x, W_gcn, A8, N, dinv);

  // ---- GCN aggregation: H8 = relu(...); D = GAT logits (fused epilogue) ----
  k_gcn <<<nwb, 256, 0, stream>>>(A8, dinv, b_gcn, offs, csr, Vs, Vd, H8, D, N);

  // ---- GAT softmax + aggregation + GAT-GEMM + SAGE-GEMM fused (32 nodes/block): -> [P8 | R] ----
  k_gat2f<<<(N+31)/32, 256, 0, stream>>>(D, H8, offs, csr, WT, b_gat, R, P8, N);

  // ---- SAGE + edge GEMM fused: S = relu(mean(P8[src]) + b + R); T2 = fp8(S @ WT3) ----
  k_sage<<<nwb, 256, 0, stream>>>(P8, R, b_sg, offs, csr, WT + (size_t)6144*8, T2, N);

  // ---- edge MLP: edge-order eval, coalesced out ----
  k_mlp <<<(E+31)/32, 256, 0, stream>>>(T2, b1, W2, b2, src, dst, out, E);
}

// Round 9
// 269.214 us; speedup vs baseline: 1.0397x; 1.0397x over previous
//
#include <hip/hip_runtime.h>
#include <math.h>

// ---------- float4 / bf16 / fp8 helpers ----------
typedef float v2f __attribute__((ext_vector_type(2)));
static __device__ __forceinline__ float4 f4s(float v){ return make_float4(v,v,v,v); }
static __device__ __forceinline__ float4 f4add(float4 a, float4 b){ return make_float4(a.x+b.x,a.y+b.y,a.z+b.z,a.w+b.w); }
static __device__ __forceinline__ float4 f4max(float4 a, float4 b){ return make_float4(fmaxf(a.x,b.x),fmaxf(a.y,b.y),fmaxf(a.z,b.z),fmaxf(a.w,b.w)); }
static __device__ __forceinline__ float4 f4scale(float4 a, float s){ return make_float4(a.x*s,a.y*s,a.z*s,a.w*s); }
static __device__ __forceinline__ float4 f4fma(float4 acc, float s, float4 b){
  acc.x += s*b.x; acc.y += s*b.y; acc.z += s*b.z; acc.w += s*b.w; return acc;
}
static __device__ __forceinline__ float4 f4relu(float4 a){ return f4max(a, f4s(0.f)); }
static __device__ __forceinline__ float4 f4leaky(float4 a){
  return make_float4(a.x>0.f?a.x:0.2f*a.x, a.y>0.f?a.y:0.2f*a.y, a.z>0.f?a.z:0.2f*a.z, a.w>0.f?a.w:0.2f*a.w);
}
static __device__ __forceinline__ float4 f4expf(float4 a){ return make_float4(__expf(a.x),__expf(a.y),__expf(a.z),__expf(a.w)); }
static __device__ __forceinline__ unsigned short f2bf(float f){
  unsigned int u = __float_as_uint(f);
  unsigned int r = (u + 0x7fffu + ((u >> 16) & 1u)) >> 16;
  return (unsigned short)r;
}
static __device__ __forceinline__ ushort4 f2bf4(float4 f){
  ushort4 r; r.x=f2bf(f.x); r.y=f2bf(f.y); r.z=f2bf(f.z); r.w=f2bf(f.w); return r;
}
// bf16x4 (as uint2) -> float4 : 4 VALU ops
static __device__ __forceinline__ float4 bfu2f4(uint2 u){
  return make_float4(__uint_as_float(u.x << 16), __uint_as_float(u.x & 0xffff0000u),
                     __uint_as_float(u.y << 16), __uint_as_float(u.y & 0xffff0000u));
}
static __device__ __forceinline__ float4 bfu2f4_lo(uint4 u){ return bfu2f4(make_uint2(u.x, u.y)); }
static __device__ __forceinline__ float4 bfu2f4_hi(uint4 u){ return bfu2f4(make_uint2(u.z, u.w)); }

typedef __attribute__((ext_vector_type(8))) unsigned short u16x8;
static __device__ __forceinline__ u16x8 f2bf8(float4 a, float4 b){
  u16x8 r;
  r[0]=f2bf(a.x); r[1]=f2bf(a.y); r[2]=f2bf(a.z); r[3]=f2bf(a.w);
  r[4]=f2bf(b.x); r[5]=f2bf(b.y); r[6]=f2bf(b.z); r[7]=f2bf(b.w);
  return r;
}
// reduce two float4 across 2 groups at lane stride 8
static __device__ __forceinline__ void red2(float4& a, float4& b){
  a.x += __shfl_xor(a.x, 8); a.y += __shfl_xor(a.y, 8);
  a.z += __shfl_xor(a.z, 8); a.w += __shfl_xor(a.w, 8);
  b.x += __shfl_xor(b.x, 8); b.y += __shfl_xor(b.y, 8);
  b.z += __shfl_xor(b.z, 8); b.w += __shfl_xor(b.w, 8);
}
// fp8 (OCP e4m3) pack/unpack
static __device__ __forceinline__ unsigned char f2fp8(float v){
  return (unsigned char)(__builtin_amdgcn_cvt_pk_fp8_f32(v, v, 0, false) & 0xff);
}
static __device__ __forceinline__ unsigned int f4_fp8x4(float4 v){
  unsigned int r = __builtin_amdgcn_cvt_pk_fp8_f32(v.x, v.y, 0, false);
  r = __builtin_amdgcn_cvt_pk_fp8_f32(v.z, v.w, r, true);
  return r;
}
static __device__ __forceinline__ float4 fp8x4_f4(unsigned int q){
  v2f lo = __builtin_amdgcn_cvt_pk_f32_fp8(q, false);
  v2f hi = __builtin_amdgcn_cvt_pk_f32_fp8(q, true);
  return make_float4(lo[0], lo[1], hi[0], hi[1]);
}
static __device__ __forceinline__ float dot8(float4 a, float4 b, const float* v){
  return a.x*v[0]+a.y*v[1]+a.z*v[2]+a.w*v[3]+b.x*v[4]+b.y*v[5]+b.z*v[6]+b.w*v[7];
}

// ---------- MFMA types ----------
typedef __attribute__((ext_vector_type(8))) short bf16x8;   // 8 bf16 = 4 VGPRs
typedef __attribute__((ext_vector_type(4))) float f32x4;

// ---------- CSR rank + (packed) bf16 weight-fragment table precompute ----------
// blocks [0, fb): rank.  blocks [fb, fb+28): WT fill (7168 slots).
// WT1 = slots [0,2048): W_gat frags (H4 layout, ld 256).
// WT2 = slots [2048,6144): [W_sl|W_sr] frags (ld 64, col split at 64).
// WT3 = slots [6144,7168): [W1top|W1bot] frags (ld 64, col split at 64).
__global__ __launch_bounds__(256) void k_rankw(const int* __restrict__ dst, int* __restrict__ cnt,
                                               int* __restrict__ rank, int E, int fb,
                                               const float* __restrict__ Wg, const float* __restrict__ Wl,
                                               const float* __restrict__ Wr, const float* __restrict__ W1a,
                                               const float* __restrict__ W1b, unsigned short* __restrict__ WT){
  if ((int)blockIdx.x < fb){
    int t = blockIdx.x*256 + threadIdx.x;
    if (t < E) rank[t] = atomicAdd(&cnt[dst[t]], 1);
    return;
  }
  int s = (blockIdx.x - fb)*256 + threadIdx.x;     // 0..7167
  int l = s & 63, f = s >> 6;
  const float* wp; int ld;
  if (s < 2048){
    int cc = f & 15, kb = f >> 4;
    int c  = cc*16 + (l & 15);
    int kr = kb*32 + ((l >> 4) << 3);
    wp = Wg + (size_t)kr*256 + c; ld = 256;
  } else if (s < 6144){
    int f2 = f - 32;
    int cc = f2 & 7, kb = f2 >> 3;
    int c  = cc*16 + (l & 15);
    int kr = kb*32 + ((l >> 4) << 3);
    wp = (c >= 64) ? (Wr + (size_t)kr*64 + (c - 64)) : (Wl + (size_t)kr*64 + c);
    ld = 64;
  } else {
    int f3 = f - 96;
    int cc = f3 & 7, kb = f3 >> 3;
    int c  = cc*16 + (l & 15);
    int kr = kb*32 + ((l >> 4) << 3);
    wp = (c >= 64) ? (W1b + (size_t)kr*64 + (c - 64)) : (W1a + (size_t)kr*64 + c);
    ld = 64;
  }
  u16x8 o;
  #pragma unroll
  for (int j = 0; j < 8; ++j) o[j] = f2bf(wp[(size_t)j*ld]);
  *(u16x8*)(WT + (size_t)s*8) = o;
}

// scan1 (blocks [0,nb)) + GAT attention basis vectors Vs/Vd (block nb, independent work packed in)
__global__ __launch_bounds__(256) void k_scan1v(const int* __restrict__ cnt, int* __restrict__ excl,
                                                int* __restrict__ bsum, int n, int nb,
                                                const float* __restrict__ Wg, const float* __restrict__ as,
                                                const float* __restrict__ ad, float* __restrict__ Vs,
                                                float* __restrict__ Vd){
  if ((int)blockIdx.x == nb){
    int t = threadIdx.x;
    int h = t >> 6, k = t & 63;
    float s = 0.f, d = 0.f;
    const float* wr = Wg + (size_t)k*256 + h*64;
    const float* ar = as + h*64;
    const float* dr = ad + h*64;
    for (int c = 0; c < 64; ++c){ float w = wr[c]; s += w*ar[c]; d += w*dr[c]; }
    Vs[t] = s; Vd[t] = d;
    return;
  }
  __shared__ int sc[256];
  int t = threadIdx.x; int i = blockIdx.x*256 + t;
  int v = (i<n)?cnt[i]:0;
  sc[t]=v; __syncthreads();
  for (int o=1;o<256;o<<=1){ int a=(t>=o)?sc[t-o]:0; __syncthreads(); sc[t]+=a; __syncthreads(); }
  if (i<n) excl[i] = sc[t]-v;
  if (t==255) bsum[blockIdx.x] = sc[t];
}
// scan3 with per-block redundant in-LDS scan of bsum
__global__ __launch_bounds__(256) void k_scan3b(const int* __restrict__ cnt, const int* __restrict__ excl,
                                                const int* __restrict__ bsum, int* __restrict__ offs,
                                                float* __restrict__ dinv, int n, int E, int nb){
  __shared__ int sb[256];
  int t = threadIdx.x;
  int v = (t<nb)?bsum[t]:0;
  sb[t]=v; __syncthreads();
  for (int o=1;o<256;o<<=1){ int a=(t>=o)?sb[t-o]:0; __syncthreads(); sb[t]+=a; __syncthreads(); }
  int bex = sb[blockIdx.x] - bsum[blockIdx.x];     // exclusive prefix for this block
  int i = blockIdx.x*256 + t;
  if (i < n){
    offs[i] = excl[i] + bex;
    dinv[i] = rsqrtf((float)cnt[i] + 1.0f);   // deg includes self-loop
    if (i == 0) offs[n] = E;
  }
}

// ---------- fused CSR-fill + GCN GEMM (independent work, one dispatch) ----------
// blocks [0, fb): csr scatter-fill.  blocks [fb, fb+gtiles): A8 = fp8(dinv * (x @ W_gcn)).
__global__ __launch_bounds__(256) void k_fillg(const int* __restrict__ src, const int* __restrict__ dstv,
                                               const int* __restrict__ offs, const int* __restrict__ rank,
                                               int* __restrict__ csr, int E, int fb,
                                               const float* __restrict__ x, const float* __restrict__ Wg,
                                               unsigned char* __restrict__ a8, int n,
                                               const float* __restrict__ dinv){
  if ((int)blockIdx.x < fb){
    int t = blockIdx.x*256 + threadIdx.x;
    if (t < E) csr[offs[dstv[t]] + rank[t]] = src[t];
    return;
  }
  // ---- GCN GEMM: K=128 (KB=4), Cout=64 (CC=4), f32 in, fp8 out, rowscale=dinv ----
  __shared__ unsigned short wb[1024*8];        // 16 KB weight frags
  int tid = threadIdx.x;
  for (int s = tid; s < 1024; s += 256){
    int l = s & 63, f = s >> 6;
    int cc = f & 3, kb = f >> 2;
    int c  = cc*16 + (l & 15);
    int kr = kb*32 + ((l >> 4) << 3);
    const float* wp = Wg + (size_t)kr*64 + c;
    unsigned short* dp = &wb[s*8];
    #pragma unroll
    for (int j = 0; j < 8; ++j) dp[j] = f2bf(wp[(size_t)j*64]);
  }
  __syncthreads();
  int wv = tid >> 6, l = tid & 63;
  int lrow = l & 15;
  int lk = (l >> 4) << 3;
  int g = blockIdx.x - fb;                     // exactly one 64-row group per block
  int r0 = (g << 6) + (wv << 4);
  int m = r0 + lrow;
  bf16x8 afr[4];
  #pragma unroll
  for (int kb = 0; kb < 4; ++kb){
    bf16x8 a = {0,0,0,0,0,0,0,0};
    if (m < n){
      const float* p = x + (size_t)m*128 + kb*32 + lk;
      float4 f0 = *(const float4*)p;
      float4 f1 = *(const float4*)(p + 4);
      a[0]=(short)f2bf(f0.x); a[1]=(short)f2bf(f0.y); a[2]=(short)f2bf(f0.z); a[3]=(short)f2bf(f0.w);
      a[4]=(short)f2bf(f1.x); a[5]=(short)f2bf(f1.y); a[6]=(short)f2bf(f1.z); a[7]=(short)f2bf(f1.w);
    }
    afr[kb] = a;
  }
  int rbase = r0 + ((l >> 4) << 2);
  float sc[4];
  #pragma unroll
  for (int r = 0; r < 4; ++r) sc[r] = (rbase + r < n) ? dinv[rbase + r] : 0.f;
  #pragma unroll
  for (int cc = 0; cc < 4; ++cc){
    f32x4 acc = {0.f, 0.f, 0.f, 0.f};
    #pragma unroll
    for (int kb = 0; kb < 4; ++kb){
      bf16x8 b = *(const bf16x8*)&wb[((kb*4 + cc)*64 + l)*8];
      acc = __builtin_amdgcn_mfma_f32_16x16x32_bf16(afr[kb], b, acc, 0, 0, 0);
    }
    int c = cc*16 + lrow;
    #pragma unroll
    for (int r = 0; r < 4; ++r){
      int rr = rbase + r;
      if (rr < n) a8[(size_t)rr*64 + c] = f2fp8(acc[r] * sc[r]);
    }
  }
}

// ---------- GCN aggregation + fused GAT-logit epilogue ----------
__global__ __launch_bounds__(256) void k_gcn(const unsigned char* __restrict__ a8, const float* __restrict__ dinv,
                                             const float* __restrict__ b, const int* __restrict__ offs,
                                             const int* __restrict__ csr, const float* __restrict__ Vs,
                                             const float* __restrict__ Vd, unsigned char* __restrict__ h8,
                                             float* __restrict__ D, int n){
  __shared__ float svs[256], svd[256];
  svs[threadIdx.x] = Vs[threadIdx.x];
  svd[threadIdx.x] = Vd[threadIdx.x];
  __syncthreads();
  int l = threadIdx.x & 63;
  int node = (((blockIdx.x*256 + threadIdx.x) >> 6) << 2) + (l >> 4);
  int l15 = l & 15;
  int grp = l15 >> 3, sub = l15 & 7;
  bool ok = node < n;
  int beg = 0, end = 0;
  float di = 0.f;
  if (ok){ beg = offs[node]; end = offs[node+1]; di = dinv[node]; }
  float4 aL0 = f4s(0.f), aH0 = f4s(0.f), aL1 = f4s(0.f), aH1 = f4s(0.f);
  int i = beg + grp;
  for (; i + 2 < end; i += 4){
    int s0 = csr[i], s1 = csr[i+2];
    uint2 u0 = *(const uint2*)(a8 + (size_t)s0*64 + (sub<<3));
    uint2 u1 = *(const uint2*)(a8 + (size_t)s1*64 + (sub<<3));
    aL0 = f4add(aL0, fp8x4_f4(u0.x)); aH0 = f4add(aH0, fp8x4_f4(u0.y));
    aL1 = f4add(aL1, fp8x4_f4(u1.x)); aH1 = f4add(aH1, fp8x4_f4(u1.y));
  }
  if (i < end){
    int s0 = csr[i];
    uint2 u0 = *(const uint2*)(a8 + (size_t)s0*64 + (sub<<3));
    aL0 = f4add(aL0, fp8x4_f4(u0.x)); aH0 = f4add(aH0, fp8x4_f4(u0.y));
  }
  float4 aL = f4add(aL0, aL1), aH = f4add(aH0, aH1);
  red2(aL, aH);
  if (ok){
    uint2 us = *(const uint2*)(a8 + (size_t)node*64 + (sub<<3));   // self (pre-scaled)
    aL = f4add(aL, fp8x4_f4(us.x)); aH = f4add(aH, fp8x4_f4(us.y));
    float4 b0 = *(const float4*)(b + (sub<<3));
    float4 b1 = *(const float4*)(b + (sub<<3) + 4);
    float4 r0 = f4relu(f4fma(b0, di, aL));                          // both groups compute H slice
    float4 r1 = f4relu(f4fma(b1, di, aH));
    if (grp == 0){
      uint2 q; q.x = f4_fp8x4(r0); q.y = f4_fp8x4(r1);
      *(uint2*)(h8 + (size_t)node*64 + (sub<<3)) = q;
    }
    // GAT logits: this group's two heads
    const float* vs0 = svs + (grp*128) + (sub<<3);   // head grp*2   (h*64 stride)
    const float* vd0 = svd + (grp*128) + (sub<<3);
    float s0 = dot8(r0, r1, vs0);
    float s1 = dot8(r0, r1, vs0 + 64);
    float d0 = dot8(r0, r1, vd0);
    float d1 = dot8(r0, r1, vd0 + 64);
    #pragma unroll
    for (int o = 1; o < 8; o <<= 1){                 // 8-lane cluster reduce (ok uniform per cluster)
      s0 += __shfl_xor(s0, o); s1 += __shfl_xor(s1, o);
      d0 += __shfl_xor(d0, o); d1 += __shfl_xor(d1, o);
    }
    if (sub == 0){
      *(float2*)(D + (size_t)node*8 + grp*2)     = make_float2(s0, s1);
      *(float2*)(D + (size_t)node*8 + 4 + grp*2) = make_float2(d0, d1);
    }
  }
}

// ---------- fused GAT softmax + aggregation + GAT-GEMM + SAGE-GEMM (32 nodes/block) ----------
// Softmax phase: 4 sequential batches of 8 nodes (wl/sl per-half-wave private -> no intra-loop
// barriers), filling a 32x264 bf16 ytile.  Then one GEMM phase over two FULL 16-row MFMA tiles
// (no pad rows): stage-A G = relu(ytile@Wg + bg) -> gtile (aliases dead wl/sl), stage-B
// [P8 | R] = G @ [Wl|Wr].  WT weight reads amortized over 32 rows.
#define GAT_CAP 128
__global__ __launch_bounds__(256) void k_gat2f(const float* __restrict__ D, const unsigned char* __restrict__ H8,
                                               const int* __restrict__ offs, const int* __restrict__ csr,
                                               const unsigned short* __restrict__ WT, const float* __restrict__ bg,
                                               unsigned short* __restrict__ R, unsigned char* __restrict__ P8, int n){
  __shared__ __align__(16) unsigned char smem_raw[8*GAT_CAP*4*4 + 8*GAT_CAP*4];  // wl 16KB + sl 4KB
  __shared__ unsigned short ytile[32][264];                                       // 16.9 KB
  float (*wl)[GAT_CAP*4] = reinterpret_cast<float (*)[GAT_CAP*4]>(smem_raw);
  int   (*sl)[GAT_CAP]   = reinterpret_cast<int (*)[GAT_CAP]>(smem_raw + 8*GAT_CAP*4*4);
  unsigned short* gtile  = reinterpret_cast<unsigned short*>(smem_raw);           // 32x264 = 16.9KB alias
  const unsigned short* WT1 = WT;               // 2048 slots (W_gat frags)
  const unsigned short* WT2 = WT + 2048*8;      // 4096 slots ([Wl|Wr] frags)
  int tid = threadIdx.x;
  int hw = tid >> 5;                 // half-wave index in block (0..7)
  int l5 = tid & 31;
  int grp = l5 >> 4;
  int sub = l5 & 15;
  // ---- softmax + aggregation: 4 batches of 8 nodes ----
  for (int batch = 0; batch < 4; ++batch){
    int lrow32 = batch*8 + hw;                  // ytile row
    int node = blockIdx.x*32 + lrow32;
    if (node < n){
      int beg = offs[node], end = offs[node+1];
      int deg = end - beg;
      float4 ed  = *(const float4*)(D + (size_t)node*8 + 4);
      float4 es0 = *(const float4*)(D + (size_t)node*8);
      float4 wself = f4expf(f4leaky(f4add(es0, ed)));
      // phase A: per-edge exp weights + src byte-offset -> LDS (first GAT_CAP), z accumulation (all)
      float4 z4 = f4s(0.f);
      for (int i = beg + l5; i < end; i += 32){
        int s = csr[i];
        float4 w = f4expf(f4leaky(f4add(*(const float4*)(D + (size_t)s*8), ed)));
        int li = i - beg;
        if (li < GAT_CAP){ *(float4*)&wl[hw][li<<2] = w; sl[hw][li] = s << 6; }  // 64 B per H8 row
        z4 = f4add(z4, w);
      }
      for (int m = 1; m < 32; m <<= 1){
        z4.x += __shfl_xor(z4.x, m); z4.y += __shfl_xor(z4.y, m);
        z4.z += __shfl_xor(z4.z, m); z4.w += __shfl_xor(z4.w, m);
      }
      z4 = f4add(z4, wself);
      // phase C: 2 edge-groups x 16 lanes per node; lane covers 4 cols (4 B) of the 64-col H8 row
      int c0b = sub << 2;           // byte offset of 4-col fp8 slice
      float4 a0 = f4s(0.f), a1 = f4s(0.f), a2 = f4s(0.f), a3 = f4s(0.f);  // per-head accumulators
      int nl = deg < GAT_CAP ? deg : GAT_CAP;
      int i = grp;
      for (; i + 2 < nl; i += 4){
        int o0 = sl[hw][i], o1 = sl[hw][i+2];
        float4 w0 = *(const float4*)&wl[hw][i<<2];
        float4 w1 = *(const float4*)&wl[hw][(i+2)<<2];
        unsigned int q0 = *(const unsigned int*)(H8 + o0 + c0b);
        unsigned int q1 = *(const unsigned int*)(H8 + o1 + c0b);
        float4 f0 = fp8x4_f4(q0);
        float4 f1 = fp8x4_f4(q1);
        a0 = f4fma(a0, w0.x, f0); a1 = f4fma(a1, w0.y, f0);
        a2 = f4fma(a2, w0.z, f0); a3 = f4fma(a3, w0.w, f0);
        a0 = f4fma(a0, w1.x, f1); a1 = f4fma(a1, w1.y, f1);
        a2 = f4fma(a2, w1.z, f1); a3 = f4fma(a3, w1.w, f1);
      }
      if (i < nl){
        float4 w0 = *(const float4*)&wl[hw][i<<2];
        float4 f0 = fp8x4_f4(*(const unsigned int*)(H8 + sl[hw][i] + c0b));
        a0 = f4fma(a0, w0.x, f0); a1 = f4fma(a1, w0.y, f0);
        a2 = f4fma(a2, w0.z, f0); a3 = f4fma(a3, w0.w, f0);
      }
      for (int j = nl + grp; j < deg; j += 2){   // LDS overflow fallback (essentially never)
        int s = csr[beg+j];
        float4 e = f4leaky(f4add(*(const float4*)(D + (size_t)s*8), ed));
        float4 w = f4expf(e);
        float4 f0 = fp8x4_f4(*(const unsigned int*)(H8 + ((size_t)s << 6) + c0b));
        a0 = f4fma(a0, w.x, f0); a1 = f4fma(a1, w.y, f0);
        a2 = f4fma(a2, w.z, f0); a3 = f4fma(a3, w.w, f0);
      }
      // cross-group reduce (lane stride 16, stays within half-wave)
      a0.x += __shfl_xor(a0.x, 16); a0.y += __shfl_xor(a0.y, 16); a0.z += __shfl_xor(a0.z, 16); a0.w += __shfl_xor(a0.w, 16);
      a1.x += __shfl_xor(a1.x, 16); a1.y += __shfl_xor(a1.y, 16); a1.z += __shfl_xor(a1.z, 16); a1.w += __shfl_xor(a1.w, 16);
      a2.x += __shfl_xor(a2.x, 16); a2.y += __shfl_xor(a2.y, 16); a2.z += __shfl_xor(a2.z, 16); a2.w += __shfl_xor(a2.w, 16);
      a3.x += __shfl_xor(a3.x, 16); a3.y += __shfl_xor(a3.y, 16); a3.z += __shfl_xor(a3.z, 16); a3.w += __shfl_xor(a3.w, 16);
      if (grp == 0){
        float4 fs = fp8x4_f4(*(const unsigned int*)(H8 + ((size_t)node << 6) + c0b));   // self term
        a0 = f4fma(a0, wself.x, fs);
        a1 = f4fma(a1, wself.y, fs);
        a2 = f4fma(a2, wself.z, fs);
        a3 = f4fma(a3, wself.w, fs);
        a0 = f4scale(a0, 1.f/(z4.x + 1e-16f));
        a1 = f4scale(a1, 1.f/(z4.y + 1e-16f));
        a2 = f4scale(a2, 1.f/(z4.z + 1e-16f));
        a3 = f4scale(a3, 1.f/(z4.w + 1e-16f));
        // Y row -> LDS (head-major, bf16, same rounding as before)
        unsigned short* yp = &ytile[lrow32][sub << 2];
        *(ushort4*)(yp)       = f2bf4(a0);
        *(ushort4*)(yp + 64)  = f2bf4(a1);
        *(ushort4*)(yp + 128) = f2bf4(a2);
        *(ushort4*)(yp + 192) = f2bf4(a3);
      }
    } else if (grp == 0){
      ushort4 z = make_ushort4(0,0,0,0);
      unsigned short* yp = &ytile[lrow32][sub << 2];
      *(ushort4*)(yp)       = z;
      *(ushort4*)(yp + 64)  = z;
      *(ushort4*)(yp + 128) = z;
      *(ushort4*)(yp + 192) = z;
    }
  }
  __syncthreads();      // ytile complete; wl/sl dead from here (gtile aliases them)
  // ---- GEMM phase over this block's 32 node-rows (two full 16-row MFMA tiles) ----
  int wv = tid >> 6, l = tid & 63;
  int lrow = l & 15;
  int lk = (l >> 4) << 3;
  int rbase4 = (l >> 4) << 2;         // 0,4,8,12
  // stage-A: G = relu(ytile@Wg + bg); wave wv owns head wv (col-chunks cc = wv*4..wv*4+3)
  bf16x8 afA[2][2];                   // [tile][kb]
  #pragma unroll
  for (int t = 0; t < 2; ++t){
    afA[t][0] = *(const bf16x8*)&ytile[t*16 + lrow][wv*64 + lk];
    afA[t][1] = *(const bf16x8*)&ytile[t*16 + lrow][wv*64 + 32 + lk];
  }
  #pragma unroll
  for (int q = 0; q < 4; ++q){
    int cc = wv*4 + q;
    bf16x8 b0 = *(const bf16x8*)&WT1[((size_t)((0*16 + cc)*64 + l))*8];
    bf16x8 b1 = *(const bf16x8*)&WT1[((size_t)((1*16 + cc)*64 + l))*8];
    int c = cc*16 + lrow;
    float bv = bg[c];
    #pragma unroll
    for (int t = 0; t < 2; ++t){
      f32x4 acc = {0.f, 0.f, 0.f, 0.f};
      acc = __builtin_amdgcn_mfma_f32_16x16x32_bf16(afA[t][0], b0, acc, 0, 0, 0);
      acc = __builtin_amdgcn_mfma_f32_16x16x32_bf16(afA[t][1], b1, acc, 0, 0, 0);
      #pragma unroll
      for (int r = 0; r < 4; ++r)
        gtile[(t*16 + rbase4 + r)*264 + c] = f2bf(fmaxf(acc[r] + bv, 0.f));
    }
  }
  __syncthreads();      // gtile complete (cross-wave columns)
  // stage-B: [P8|R] = G @ [Wl|Wr]; wave wv owns cc = wv*2, wv*2+1; B-frags shared across tiles
  bf16x8 afb[2][8];
  #pragma unroll
  for (int t = 0; t < 2; ++t)
    #pragma unroll
    for (int kb = 0; kb < 8; ++kb)
      afb[t][kb] = *(const bf16x8*)&gtile[(t*16 + lrow)*264 + kb*32 + lk];
  #pragma unroll
  for (int q = 0; q < 2; ++q){
    int cc = wv*2 + q;
    f32x4 acc0 = {0.f, 0.f, 0.f, 0.f};
    f32x4 acc1 = {0.f, 0.f, 0.f, 0.f};
    #pragma unroll
    for (int kb = 0; kb < 8; ++kb){
      bf16x8 b = *(const bf16x8*)&WT2[((size_t)((kb*8 + cc)*64 + l))*8];
      acc0 = __builtin_amdgcn_mfma_f32_16x16x32_bf16(afb[0][kb], b, acc0, 0, 0, 0);
      acc1 = __builtin_amdgcn_mfma_f32_16x16x32_bf16(afb[1][kb], b, acc1, 0, 0, 0);
    }
    int c = cc*16 + lrow;
    #pragma unroll
    for (int t = 0; t < 2; ++t){
      const f32x4& acc = t ? acc1 : acc0;
      #pragma unroll
      for (int r = 0; r < 4; ++r){
        int nd = blockIdx.x*32 + t*16 + rbase4 + r;
        if (nd < n){
          float v = acc[r];
          if (c < 64) P8[(size_t)nd*64 + c] = f2fp8(v);
          else        R[(size_t)nd*64 + (c - 64)] = f2bf(v);
        }
      }
    }
  }
}

// ---------- SAGE aggregation + fused edge-MLP GEMM epilogue ----------
// W1 frags read from precomputed L2-resident WT3 (no per-block staging, LDS = 2.3 KB).
__global__ __launch_bounds__(256) void k_sage(const unsigned char* __restrict__ P8, const unsigned short* __restrict__ R,
                                              const float* __restrict__ b, const int* __restrict__ offs,
                                              const int* __restrict__ csr, const unsigned short* __restrict__ WT3,
                                              unsigned char* __restrict__ T2, int n){
  __shared__ unsigned short stile[16][72];     // 16 S rows bf16, pad 72 (144 B stride)
  int tid = threadIdx.x;
  int wv = tid >> 6, l = tid & 63;
  int base = blockIdx.x*16;
  int lrow16 = (wv << 2) + (l >> 4);           // block-local row 0..15
  int node = base + lrow16;
  int l15 = l & 15;
  int grp = l15 >> 3, sub = l15 & 7;
  bool ok = node < n;
  int beg = 0, end = 0;
  if (ok){ beg = offs[node]; end = offs[node+1]; }
  float4 aL0 = f4s(0.f), aH0 = f4s(0.f), aL1 = f4s(0.f), aH1 = f4s(0.f);
  int i = beg + grp;
  for (; i + 2 < end; i += 4){
    int s0 = csr[i], s1 = csr[i+2];
    uint2 u0 = *(const uint2*)(P8 + (size_t)s0*64 + (sub<<3));
    uint2 u1 = *(const uint2*)(P8 + (size_t)s1*64 + (sub<<3));
    aL0 = f4add(aL0, fp8x4_f4(u0.x)); aH0 = f4add(aH0, fp8x4_f4(u0.y));
    aL1 = f4add(aL1, fp8x4_f4(u1.x)); aH1 = f4add(aH1, fp8x4_f4(u1.y));
  }
  if (i < end){
    int s0 = csr[i];
    uint2 u0 = *(const uint2*)(P8 + (size_t)s0*64 + (sub<<3));
    aL0 = f4add(aL0, fp8x4_f4(u0.x)); aH0 = f4add(aH0, fp8x4_f4(u0.y));
  }
  float4 aL = f4add(aL0, aL1), aH = f4add(aH0, aH1);
  red2(aL, aH);
  float4 r0 = f4s(0.f), r1 = f4s(0.f);
  if (ok){
    float minv = 1.f / fmaxf((float)(end - beg), 1.f);
    uint4 ur = *(const uint4*)(R + (size_t)node*64 + (sub<<3));
    float4 b0 = *(const float4*)(b + (sub<<3));
    float4 b1 = *(const float4*)(b + (sub<<3) + 4);
    r0 = f4relu(f4add(f4fma(b0, minv, aL), bfu2f4_lo(ur)));
    r1 = f4relu(f4add(f4fma(b1, minv, aH), bfu2f4_hi(ur)));
  }
  if (grp == 0) *(u16x8*)&stile[lrow16][sub << 3] = f2bf8(r0, r1);
  __syncthreads();
  // MFMA epilogue: 16 rows x 128 cols, K=64; waves split the 8 col-chunks (2 each)
  int lrow = l & 15, lk = (l >> 4) << 3;
  bf16x8 af0 = *(const bf16x8*)&stile[lrow][lk];
  bf16x8 af1 = *(const bf16x8*)&stile[lrow][32 + lk];
  int rbase = (l >> 4) << 2;
  #pragma unroll
  for (int q = 0; q < 2; ++q){
    int cc = wv*2 + q;
    f32x4 acc = {0.f, 0.f, 0.f, 0.f};
    acc = __builtin_amdgcn_mfma_f32_16x16x32_bf16(af0, *(const bf16x8*)&WT3[((size_t)((0*8 + cc)*64 + l))*8], acc, 0, 0, 0);
    acc = __builtin_amdgcn_mfma_f32_16x16x32_bf16(af1, *(const bf16x8*)&WT3[((size_t)((1*8 + cc)*64 + l))*8], acc, 0, 0, 0);
    int c = cc*16 + lrow;
    #pragma unroll
    for (int r = 0; r < 4; ++r){
      int nd = base + rbase + r;
      if (nd < n) T2[(size_t)nd*128 + c] = f2fp8(acc[r]);
    }
  }
}

// ---------- edge MLP, edge-order: 8 lanes/edge; T2 = [U|V] fp8 rows of 128 B ----------
__global__ __launch_bounds__(256) void k_mlp(const unsigned char* __restrict__ T2,
                                             const float* __restrict__ b1, const float* __restrict__ W2,
                                             const float* __restrict__ b2, const int* __restrict__ src,
                                             const int* __restrict__ dst, float* __restrict__ out, int E){
  int t = threadIdx.x;
  int e = blockIdx.x*32 + (t >> 3);
  if (e >= E) return;
  int sub = t & 7;
  int s = src[e], d = dst[e];
  uint2 uu = *(const uint2*)(T2 + (size_t)s*128 + (sub<<3));        // 8 fp8 of U[s]
  uint2 vv = *(const uint2*)(T2 + (size_t)d*128 + 64 + (sub<<3));   // 8 fp8 of V[d]
  float4 u0 = fp8x4_f4(uu.x), u1 = fp8x4_f4(uu.y);
  float4 v0 = fp8x4_f4(vv.x), v1 = fp8x4_f4(vv.y);
  float4 bb0 = *(const float4*)(b1 + (sub<<3));
  float4 bb1 = *(const float4*)(b1 + (sub<<3) + 4);
  float4 w0 = *(const float4*)(W2 + (sub<<3));
  float4 w1 = *(const float4*)(W2 + (sub<<3) + 4);
  float4 ta = f4relu(f4add(f4add(u0, v0), bb0));
  float4 tb = f4relu(f4add(f4add(u1, v1), bb1));
  float p = ta.x*w0.x + ta.y*w0.y + ta.z*w0.z + ta.w*w0.w
          + tb.x*w1.x + tb.y*w1.y + tb.z*w1.z + tb.w*w1.w;
  p += __shfl_xor(p, 1);
  p += __shfl_xor(p, 2);
  p += __shfl_xor(p, 4);
  if (sub == 0) out[e] = 1.f / (1.f + __expf(-(p + b2[0])));
}

extern "C" void kernel_launch(void* const* d_in, const int* in_sizes, int n_in,
                              void* d_out, int out_size, void* d_ws, size_t ws_size,
                              hipStream_t stream){
  const float* x     = (const float*)d_in[0];
  const int*   eidx  = (const int*)  d_in[1];
  const float* W_gcn = (const float*)d_in[2];
  const float* b_gcn = (const float*)d_in[3];
  const float* W_gat = (const float*)d_in[4];
  const float* att_s = (const float*)d_in[5];
  const float* att_d = (const float*)d_in[6];
  const float* b_gat = (const float*)d_in[7];
  const float* W_sl  = (const float*)d_in[8];
  const float* b_sg  = (const float*)d_in[9];
  const float* W_sr  = (const float*)d_in[10];
  const float* W1    = (const float*)d_in[11];
  const float* b1    = (const float*)d_in[12];
  const float* W2    = (const float*)d_in[13];
  const float* b2    = (const float*)d_in[14];
  float* out = (float*)d_out;

  const int N = in_sizes[0] / 128;
  const int E = in_sizes[1] / 2;
  const int* src = eidx;
  const int* dst = eidx + E;

  // ---- workspace layout: f32, then bf16, then fp8, then int ----
  float* ws   = (float*)d_ws;
  float* dinv = ws;                        // N
  float* D    = dinv + (size_t)N;          // N*8  (a_s | a_d)
  float* Vs   = D + (size_t)N*8;           // 256
  float* Vd   = Vs + 256;                  // 256
  unsigned short* WT = (unsigned short*)(Vd + 256);        // 7168*8 bf16 weight frag tables (112 KB)
  unsigned short* R  = WT + (size_t)7168*8;// N*64  bf16 (SAGE root term, compact)
  unsigned char*  A8 = (unsigned char*)(R + (size_t)N*64); // N*64  fp8 (dinv * x @ W_gcn)
  unsigned char*  H8 = A8 + (size_t)N*64;  // N*64  fp8 (GCN out shadow)
  unsigned char*  P8 = H8 + (size_t)N*64;  // N*64  fp8 (SAGE neighbor term, compact)
  unsigned char*  T2 = P8 + (size_t)N*64;  // N*128 fp8 (U | V)
  int* cnt  = (int*)(T2 + (size_t)N*128);  // N
  int* excl = cnt + N;                     // N
  int* bsum = excl + N;                    // 256
  int* offs = bsum + 256;                  // N+1
  int* rank = offs + N + 1;                // E
  int* csr  = rank + E;                    // E

  const int nb = (N + 255) / 256;
  const int fb = (E + 255) / 256;
  const int gtiles = (N + 63) / 64;
  const int nwb = (N + 15) / 16;          // 4 nodes/wave kernels (16 nodes/block)

  // ---- CSR build (+ packed independent work: WT frag tables, Vs/Vd basis, GCN GEMM) ----
  hipMemsetAsync(cnt, 0, (size_t)N*sizeof(int), stream);
  k_rankw <<<fb + 28, 256, 0, stream>>>(dst, cnt, rank, E, fb, W_gat, W_sl, W_sr,
                                        W1, W1 + 64*64, WT);
  k_scan1v<<<nb + 1, 256, 0, stream>>>(cnt, excl, bsum, N, nb, W_gat, att_s, att_d, Vs, Vd);
  k_scan3b<<<nb, 256, 0, stream>>>(cnt, excl, bsum, offs, dinv, N, E, nb);
  k_fillg <<<fb + gtiles, 256, 0, stream>>>(src, dst, offs, rank, csr, E, fb,
                                            x, W_gcn, A8, N, dinv);

  // ---- GCN aggregation: H8 = relu(...); D = GAT logits (fused epilogue) ----
  k_gcn <<<nwb, 256, 0, stream>>>(A8, dinv, b_gcn, offs, csr, Vs, Vd, H8, D, N);

  // ---- GAT softmax + aggregation + GAT-GEMM + SAGE-GEMM fused (32 nodes/block): -> [P8 | R] ----
  k_gat2f<<<(N+31)/32, 256, 0, stream>>>(D, H8, offs, csr, WT, b_gat, R, P8, N);

  // ---- SAGE + edge GEMM fused: S = relu(mean(P8[src]) + b + R); T2 = fp8(S @ WT3) ----
  k_sage<<<nwb, 256, 0, stream>>>(P8, R, b_sg, offs, csr, WT + (size_t)6144*8, T2, N);

  // ---- edge MLP: edge-order eval, coalesced out ----
  k_mlp <<<(E+31)/32, 256, 0, stream>>>(T2, b1, W2, b2, src, dst, out, E);
}

// Round 10
// 264.625 us; speedup vs baseline: 1.0577x; 1.0173x over previous
//
#include <hip/hip_runtime.h>
#include <math.h>

// ---------- float4 / bf16 / fp8 helpers ----------
typedef float v2f __attribute__((ext_vector_type(2)));
static __device__ __forceinline__ float4 f4s(float v){ return make_float4(v,v,v,v); }
static __device__ __forceinline__ float4 f4add(float4 a, float4 b){ return make_float4(a.x+b.x,a.y+b.y,a.z+b.z,a.w+b.w); }
static __device__ __forceinline__ float4 f4max(float4 a, float4 b){ return make_float4(fmaxf(a.x,b.x),fmaxf(a.y,b.y),fmaxf(a.z,b.z),fmaxf(a.w,b.w)); }
static __device__ __forceinline__ float4 f4scale(float4 a, float s){ return make_float4(a.x*s,a.y*s,a.z*s,a.w*s); }
static __device__ __forceinline__ float4 f4fma(float4 acc, float s, float4 b){
  acc.x += s*b.x; acc.y += s*b.y; acc.z += s*b.z; acc.w += s*b.w; return acc;
}
static __device__ __forceinline__ float4 f4relu(float4 a){ return f4max(a, f4s(0.f)); }
static __device__ __forceinline__ float4 f4leaky(float4 a){
  return make_float4(a.x>0.f?a.x:0.2f*a.x, a.y>0.f?a.y:0.2f*a.y, a.z>0.f?a.z:0.2f*a.z, a.w>0.f?a.w:0.2f*a.w);
}
static __device__ __forceinline__ float4 f4expf(float4 a){ return make_float4(__expf(a.x),__expf(a.y),__expf(a.z),__expf(a.w)); }
static __device__ __forceinline__ unsigned short f2bf(float f){
  unsigned int u = __float_as_uint(f);
  unsigned int r = (u + 0x7fffu + ((u >> 16) & 1u)) >> 16;
  return (unsigned short)r;
}
static __device__ __forceinline__ ushort4 f2bf4(float4 f){
  ushort4 r; r.x=f2bf(f.x); r.y=f2bf(f.y); r.z=f2bf(f.z); r.w=f2bf(f.w); return r;
}
// bf16x4 (as uint2) -> float4 : 4 VALU ops
static __device__ __forceinline__ float4 bfu2f4(uint2 u){
  return make_float4(__uint_as_float(u.x << 16), __uint_as_float(u.x & 0xffff0000u),
                     __uint_as_float(u.y << 16), __uint_as_float(u.y & 0xffff0000u));
}
static __device__ __forceinline__ float4 bfu2f4_lo(uint4 u){ return bfu2f4(make_uint2(u.x, u.y)); }
static __device__ __forceinline__ float4 bfu2f4_hi(uint4 u){ return bfu2f4(make_uint2(u.z, u.w)); }

typedef __attribute__((ext_vector_type(8))) unsigned short u16x8;
static __device__ __forceinline__ u16x8 f2bf8(float4 a, float4 b){
  u16x8 r;
  r[0]=f2bf(a.x); r[1]=f2bf(a.y); r[2]=f2bf(a.z); r[3]=f2bf(a.w);
  r[4]=f2bf(b.x); r[5]=f2bf(b.y); r[6]=f2bf(b.z); r[7]=f2bf(b.w);
  return r;
}
// reduce two float4 across 2 groups at lane stride 8
static __device__ __forceinline__ void red2(float4& a, float4& b){
  a.x += __shfl_xor(a.x, 8); a.y += __shfl_xor(a.y, 8);
  a.z += __shfl_xor(a.z, 8); a.w += __shfl_xor(a.w, 8);
  b.x += __shfl_xor(b.x, 8); b.y += __shfl_xor(b.y, 8);
  b.z += __shfl_xor(b.z, 8); b.w += __shfl_xor(b.w, 8);
}
// fp8 (OCP e4m3) pack/unpack
static __device__ __forceinline__ unsigned char f2fp8(float v){
  return (unsigned char)(__builtin_amdgcn_cvt_pk_fp8_f32(v, v, 0, false) & 0xff);
}
static __device__ __forceinline__ unsigned int f4_fp8x4(float4 v){
  unsigned int r = __builtin_amdgcn_cvt_pk_fp8_f32(v.x, v.y, 0, false);
  r = __builtin_amdgcn_cvt_pk_fp8_f32(v.z, v.w, r, true);
  return r;
}
static __device__ __forceinline__ float4 fp8x4_f4(unsigned int q){
  v2f lo = __builtin_amdgcn_cvt_pk_f32_fp8(q, false);
  v2f hi = __builtin_amdgcn_cvt_pk_f32_fp8(q, true);
  return make_float4(lo[0], lo[1], hi[0], hi[1]);
}
static __device__ __forceinline__ float dot8(float4 a, float4 b, const float* v){
  return a.x*v[0]+a.y*v[1]+a.z*v[2]+a.w*v[3]+b.x*v[4]+b.y*v[5]+b.z*v[6]+b.w*v[7];
}

// ---------- MFMA types ----------
typedef __attribute__((ext_vector_type(8))) short bf16x8;   // 8 bf16 = 4 VGPRs
typedef __attribute__((ext_vector_type(4))) float f32x4;

// ---------- CSR rank + (packed) bf16 weight-fragment table precompute ----------
// blocks [0, fb): rank.  blocks [fb, fb+28): WT fill (7168 slots).
// WT1 = slots [0,2048): W_gat frags (H4 layout, ld 256).
// WT2 = slots [2048,6144): [W_sl|W_sr] frags (ld 64, col split at 64).
// WT3 = slots [6144,7168): [W1top|W1bot] frags (ld 64, col split at 64).
__global__ __launch_bounds__(256) void k_rankw(const int* __restrict__ dst, int* __restrict__ cnt,
                                               int* __restrict__ rank, int E, int fb,
                                               const float* __restrict__ Wg, const float* __restrict__ Wl,
                                               const float* __restrict__ Wr, const float* __restrict__ W1a,
                                               const float* __restrict__ W1b, unsigned short* __restrict__ WT){
  if ((int)blockIdx.x < fb){
    int t = blockIdx.x*256 + threadIdx.x;
    if (t < E) rank[t] = atomicAdd(&cnt[dst[t]], 1);
    return;
  }
  int s = (blockIdx.x - fb)*256 + threadIdx.x;     // 0..7167
  int l = s & 63, f = s >> 6;
  const float* wp; int ld;
  if (s < 2048){
    int cc = f & 15, kb = f >> 4;
    int c  = cc*16 + (l & 15);
    int kr = kb*32 + ((l >> 4) << 3);
    wp = Wg + (size_t)kr*256 + c; ld = 256;
  } else if (s < 6144){
    int f2 = f - 32;
    int cc = f2 & 7, kb = f2 >> 3;
    int c  = cc*16 + (l & 15);
    int kr = kb*32 + ((l >> 4) << 3);
    wp = (c >= 64) ? (Wr + (size_t)kr*64 + (c - 64)) : (Wl + (size_t)kr*64 + c);
    ld = 64;
  } else {
    int f3 = f - 96;
    int cc = f3 & 7, kb = f3 >> 3;
    int c  = cc*16 + (l & 15);
    int kr = kb*32 + ((l >> 4) << 3);
    wp = (c >= 64) ? (W1b + (size_t)kr*64 + (c - 64)) : (W1a + (size_t)kr*64 + c);
    ld = 64;
  }
  u16x8 o;
  #pragma unroll
  for (int j = 0; j < 8; ++j) o[j] = f2bf(wp[(size_t)j*ld]);
  *(u16x8*)(WT + (size_t)s*8) = o;
}

// scan1 (blocks [0,nb)) + GAT attention basis vectors Vs/Vd (block nb, independent work packed in)
__global__ __launch_bounds__(256) void k_scan1v(const int* __restrict__ cnt, int* __restrict__ excl,
                                                int* __restrict__ bsum, int n, int nb,
                                                const float* __restrict__ Wg, const float* __restrict__ as,
                                                const float* __restrict__ ad, float* __restrict__ Vs,
                                                float* __restrict__ Vd){
  if ((int)blockIdx.x == nb){
    int t = threadIdx.x;
    int h = t >> 6, k = t & 63;
    float s = 0.f, d = 0.f;
    const float* wr = Wg + (size_t)k*256 + h*64;
    const float* ar = as + h*64;
    const float* dr = ad + h*64;
    for (int c = 0; c < 64; ++c){ float w = wr[c]; s += w*ar[c]; d += w*dr[c]; }
    Vs[t] = s; Vd[t] = d;
    return;
  }
  __shared__ int sc[256];
  int t = threadIdx.x; int i = blockIdx.x*256 + t;
  int v = (i<n)?cnt[i]:0;
  sc[t]=v; __syncthreads();
  for (int o=1;o<256;o<<=1){ int a=(t>=o)?sc[t-o]:0; __syncthreads(); sc[t]+=a; __syncthreads(); }
  if (i<n) excl[i] = sc[t]-v;
  if (t==255) bsum[blockIdx.x] = sc[t];
}
// scan3 with per-block redundant in-LDS scan of bsum
__global__ __launch_bounds__(256) void k_scan3b(const int* __restrict__ cnt, const int* __restrict__ excl,
                                                const int* __restrict__ bsum, int* __restrict__ offs,
                                                float* __restrict__ dinv, int n, int E, int nb){
  __shared__ int sb[256];
  int t = threadIdx.x;
  int v = (t<nb)?bsum[t]:0;
  sb[t]=v; __syncthreads();
  for (int o=1;o<256;o<<=1){ int a=(t>=o)?sb[t-o]:0; __syncthreads(); sb[t]+=a; __syncthreads(); }
  int bex = sb[blockIdx.x] - bsum[blockIdx.x];     // exclusive prefix for this block
  int i = blockIdx.x*256 + t;
  if (i < n){
    offs[i] = excl[i] + bex;
    dinv[i] = rsqrtf((float)cnt[i] + 1.0f);   // deg includes self-loop
    if (i == 0) offs[n] = E;
  }
}

// ---------- fused CSR-fill + GCN GEMM (independent work, one dispatch) ----------
// blocks [0, fb): csr scatter-fill.  blocks [fb, fb+gtiles): A8 = fp8(dinv * (x @ W_gcn)).
__global__ __launch_bounds__(256) void k_fillg(const int* __restrict__ src, const int* __restrict__ dstv,
                                               const int* __restrict__ offs, const int* __restrict__ rank,
                                               int* __restrict__ csr, int E, int fb,
                                               const float* __restrict__ x, const float* __restrict__ Wg,
                                               unsigned char* __restrict__ a8, int n,
                                               const float* __restrict__ dinv){
  if ((int)blockIdx.x < fb){
    int t = blockIdx.x*256 + threadIdx.x;
    if (t < E) csr[offs[dstv[t]] + rank[t]] = src[t];
    return;
  }
  // ---- GCN GEMM: K=128 (KB=4), Cout=64 (CC=4), f32 in, fp8 out, rowscale=dinv ----
  __shared__ unsigned short wb[1024*8];        // 16 KB weight frags
  int tid = threadIdx.x;
  for (int s = tid; s < 1024; s += 256){
    int l = s & 63, f = s >> 6;
    int cc = f & 3, kb = f >> 2;
    int c  = cc*16 + (l & 15);
    int kr = kb*32 + ((l >> 4) << 3);
    const float* wp = Wg + (size_t)kr*64 + c;
    unsigned short* dp = &wb[s*8];
    #pragma unroll
    for (int j = 0; j < 8; ++j) dp[j] = f2bf(wp[(size_t)j*64]);
  }
  __syncthreads();
  int wv = tid >> 6, l = tid & 63;
  int lrow = l & 15;
  int lk = (l >> 4) << 3;
  int g = blockIdx.x - fb;                     // exactly one 64-row group per block
  int r0 = (g << 6) + (wv << 4);
  int m = r0 + lrow;
  bf16x8 afr[4];
  #pragma unroll
  for (int kb = 0; kb < 4; ++kb){
    bf16x8 a = {0,0,0,0,0,0,0,0};
    if (m < n){
      const float* p = x + (size_t)m*128 + kb*32 + lk;
      float4 f0 = *(const float4*)p;
      float4 f1 = *(const float4*)(p + 4);
      a[0]=(short)f2bf(f0.x); a[1]=(short)f2bf(f0.y); a[2]=(short)f2bf(f0.z); a[3]=(short)f2bf(f0.w);
      a[4]=(short)f2bf(f1.x); a[5]=(short)f2bf(f1.y); a[6]=(short)f2bf(f1.z); a[7]=(short)f2bf(f1.w);
    }
    afr[kb] = a;
  }
  int rbase = r0 + ((l >> 4) << 2);
  float sc[4];
  #pragma unroll
  for (int r = 0; r < 4; ++r) sc[r] = (rbase + r < n) ? dinv[rbase + r] : 0.f;
  #pragma unroll
  for (int cc = 0; cc < 4; ++cc){
    f32x4 acc = {0.f, 0.f, 0.f, 0.f};
    #pragma unroll
    for (int kb = 0; kb < 4; ++kb){
      bf16x8 b = *(const bf16x8*)&wb[((kb*4 + cc)*64 + l)*8];
      acc = __builtin_amdgcn_mfma_f32_16x16x32_bf16(afr[kb], b, acc, 0, 0, 0);
    }
    int c = cc*16 + lrow;
    #pragma unroll
    for (int r = 0; r < 4; ++r){
      int rr = rbase + r;
      if (rr < n) a8[(size_t)rr*64 + c] = f2fp8(acc[r] * sc[r]);
    }
  }
}

// ---------- GCN aggregation + fused GAT-logit epilogue ----------
// Gather loop 4-deep (4 rows in flight); per-chain accumulation order identical to 2-deep.
__global__ __launch_bounds__(256) void k_gcn(const unsigned char* __restrict__ a8, const float* __restrict__ dinv,
                                             const float* __restrict__ b, const int* __restrict__ offs,
                                             const int* __restrict__ csr, const float* __restrict__ Vs,
                                             const float* __restrict__ Vd, unsigned char* __restrict__ h8,
                                             float* __restrict__ D, int n){
  __shared__ float svs[256], svd[256];
  svs[threadIdx.x] = Vs[threadIdx.x];
  svd[threadIdx.x] = Vd[threadIdx.x];
  __syncthreads();
  int l = threadIdx.x & 63;
  int node = (((blockIdx.x*256 + threadIdx.x) >> 6) << 2) + (l >> 4);
  int l15 = l & 15;
  int grp = l15 >> 3, sub = l15 & 7;
  bool ok = node < n;
  int beg = 0, end = 0;
  float di = 0.f;
  if (ok){ beg = offs[node]; end = offs[node+1]; di = dinv[node]; }
  float4 aL0 = f4s(0.f), aH0 = f4s(0.f), aL1 = f4s(0.f), aH1 = f4s(0.f);
  int i = beg + grp;
  for (; i + 6 < end; i += 8){
    int s0 = csr[i], s1 = csr[i+2], s2 = csr[i+4], s3 = csr[i+6];
    uint2 u0 = *(const uint2*)(a8 + (size_t)s0*64 + (sub<<3));
    uint2 u1 = *(const uint2*)(a8 + (size_t)s1*64 + (sub<<3));
    uint2 u2 = *(const uint2*)(a8 + (size_t)s2*64 + (sub<<3));
    uint2 u3 = *(const uint2*)(a8 + (size_t)s3*64 + (sub<<3));
    aL0 = f4add(aL0, fp8x4_f4(u0.x)); aH0 = f4add(aH0, fp8x4_f4(u0.y));
    aL1 = f4add(aL1, fp8x4_f4(u1.x)); aH1 = f4add(aH1, fp8x4_f4(u1.y));
    aL0 = f4add(aL0, fp8x4_f4(u2.x)); aH0 = f4add(aH0, fp8x4_f4(u2.y));
    aL1 = f4add(aL1, fp8x4_f4(u3.x)); aH1 = f4add(aH1, fp8x4_f4(u3.y));
  }
  for (; i + 2 < end; i += 4){
    int s0 = csr[i], s1 = csr[i+2];
    uint2 u0 = *(const uint2*)(a8 + (size_t)s0*64 + (sub<<3));
    uint2 u1 = *(const uint2*)(a8 + (size_t)s1*64 + (sub<<3));
    aL0 = f4add(aL0, fp8x4_f4(u0.x)); aH0 = f4add(aH0, fp8x4_f4(u0.y));
    aL1 = f4add(aL1, fp8x4_f4(u1.x)); aH1 = f4add(aH1, fp8x4_f4(u1.y));
  }
  if (i < end){
    int s0 = csr[i];
    uint2 u0 = *(const uint2*)(a8 + (size_t)s0*64 + (sub<<3));
    aL0 = f4add(aL0, fp8x4_f4(u0.x)); aH0 = f4add(aH0, fp8x4_f4(u0.y));
  }
  float4 aL = f4add(aL0, aL1), aH = f4add(aH0, aH1);
  red2(aL, aH);
  if (ok){
    uint2 us = *(const uint2*)(a8 + (size_t)node*64 + (sub<<3));   // self (pre-scaled)
    aL = f4add(aL, fp8x4_f4(us.x)); aH = f4add(aH, fp8x4_f4(us.y));
    float4 b0 = *(const float4*)(b + (sub<<3));
    float4 b1 = *(const float4*)(b + (sub<<3) + 4);
    float4 r0 = f4relu(f4fma(b0, di, aL));                          // both groups compute H slice
    float4 r1 = f4relu(f4fma(b1, di, aH));
    if (grp == 0){
      uint2 q; q.x = f4_fp8x4(r0); q.y = f4_fp8x4(r1);
      *(uint2*)(h8 + (size_t)node*64 + (sub<<3)) = q;
    }
    // GAT logits: this group's two heads
    const float* vs0 = svs + (grp*128) + (sub<<3);   // head grp*2   (h*64 stride)
    const float* vd0 = svd + (grp*128) + (sub<<3);
    float s0 = dot8(r0, r1, vs0);
    float s1 = dot8(r0, r1, vs0 + 64);
    float d0 = dot8(r0, r1, vd0);
    float d1 = dot8(r0, r1, vd0 + 64);
    #pragma unroll
    for (int o = 1; o < 8; o <<= 1){                 // 8-lane cluster reduce (ok uniform per cluster)
      s0 += __shfl_xor(s0, o); s1 += __shfl_xor(s1, o);
      d0 += __shfl_xor(d0, o); d1 += __shfl_xor(d1, o);
    }
    if (sub == 0){
      *(float2*)(D + (size_t)node*8 + grp*2)     = make_float2(s0, s1);
      *(float2*)(D + (size_t)node*8 + 4 + grp*2) = make_float2(d0, d1);
    }
  }
}

// ---------- fused GAT softmax + aggregation + GAT-GEMM + SAGE-GEMM (32 nodes/block) ----------
// Phase C now chunk-4 (4 H8 gathers in flight); tail edges index-clamped with w=0 (exact no-op,
// accumulators are non-negative). Per-accumulator summation order unchanged -> bit-identical.
#define GAT_CAP 128
__global__ __launch_bounds__(256) void k_gat2f(const float* __restrict__ D, const unsigned char* __restrict__ H8,
                                               const int* __restrict__ offs, const int* __restrict__ csr,
                                               const unsigned short* __restrict__ WT, const float* __restrict__ bg,
                                               unsigned short* __restrict__ R, unsigned char* __restrict__ P8, int n){
  __shared__ __align__(16) unsigned char smem_raw[8*GAT_CAP*4*4 + 8*GAT_CAP*4];  // wl 16KB + sl 4KB
  __shared__ unsigned short ytile[32][264];                                       // 16.9 KB
  float (*wl)[GAT_CAP*4] = reinterpret_cast<float (*)[GAT_CAP*4]>(smem_raw);
  int   (*sl)[GAT_CAP]   = reinterpret_cast<int (*)[GAT_CAP]>(smem_raw + 8*GAT_CAP*4*4);
  unsigned short* gtile  = reinterpret_cast<unsigned short*>(smem_raw);           // 32x264 = 16.9KB alias
  const unsigned short* WT1 = WT;               // 2048 slots (W_gat frags)
  const unsigned short* WT2 = WT + 2048*8;      // 4096 slots ([Wl|Wr] frags)
  int tid = threadIdx.x;
  int hw = tid >> 5;                 // half-wave index in block (0..7)
  int l5 = tid & 31;
  int grp = l5 >> 4;
  int sub = l5 & 15;
  // ---- softmax + aggregation: 4 batches of 8 nodes ----
  for (int batch = 0; batch < 4; ++batch){
    int lrow32 = batch*8 + hw;                  // ytile row
    int node = blockIdx.x*32 + lrow32;
    if (node < n){
      int beg = offs[node], end = offs[node+1];
      int deg = end - beg;
      float4 ed  = *(const float4*)(D + (size_t)node*8 + 4);
      float4 es0 = *(const float4*)(D + (size_t)node*8);
      float4 wself = f4expf(f4leaky(f4add(es0, ed)));
      // phase A: per-edge exp weights + src byte-offset -> LDS (first GAT_CAP), z accumulation (all)
      float4 z4 = f4s(0.f);
      for (int i = beg + l5; i < end; i += 32){
        int s = csr[i];
        float4 w = f4expf(f4leaky(f4add(*(const float4*)(D + (size_t)s*8), ed)));
        int li = i - beg;
        if (li < GAT_CAP){ *(float4*)&wl[hw][li<<2] = w; sl[hw][li] = s << 6; }  // 64 B per H8 row
        z4 = f4add(z4, w);
      }
      for (int m = 1; m < 32; m <<= 1){
        z4.x += __shfl_xor(z4.x, m); z4.y += __shfl_xor(z4.y, m);
        z4.z += __shfl_xor(z4.z, m); z4.w += __shfl_xor(z4.w, m);
      }
      z4 = f4add(z4, wself);
      // phase C: 2 edge-groups x 16 lanes per node; chunk-4, 4 gathers in flight
      int c0b = sub << 2;           // byte offset of 4-col fp8 slice
      float4 a0 = f4s(0.f), a1 = f4s(0.f), a2 = f4s(0.f), a3 = f4s(0.f);  // per-head accumulators
      int nl = deg < GAT_CAP ? deg : GAT_CAP;
      int nm = nl - 1;
      for (int i0 = grp; i0 < nl; i0 += 8){
        int i1 = i0 + 2, i2 = i0 + 4, i3 = i0 + 6;
        int j1 = i1 > nm ? nm : i1;
        int j2 = i2 > nm ? nm : i2;
        int j3 = i3 > nm ? nm : i3;
        int o0 = sl[hw][i0], o1 = sl[hw][j1], o2 = sl[hw][j2], o3 = sl[hw][j3];
        unsigned int q0 = *(const unsigned int*)(H8 + o0 + c0b);
        unsigned int q1 = *(const unsigned int*)(H8 + o1 + c0b);
        unsigned int q2 = *(const unsigned int*)(H8 + o2 + c0b);
        unsigned int q3 = *(const unsigned int*)(H8 + o3 + c0b);
        float4 w0 = *(const float4*)&wl[hw][i0<<2];
        float4 w1 = *(const float4*)&wl[hw][j1<<2];
        float4 w2 = *(const float4*)&wl[hw][j2<<2];
        float4 w3 = *(const float4*)&wl[hw][j3<<2];
        if (i1 > nm) w1 = f4s(0.f);
        if (i2 > nm) w2 = f4s(0.f);
        if (i3 > nm) w3 = f4s(0.f);
        float4 f0 = fp8x4_f4(q0);
        float4 f1 = fp8x4_f4(q1);
        float4 f2 = fp8x4_f4(q2);
        float4 f3 = fp8x4_f4(q3);
        a0 = f4fma(a0, w0.x, f0); a1 = f4fma(a1, w0.y, f0);
        a2 = f4fma(a2, w0.z, f0); a3 = f4fma(a3, w0.w, f0);
        a0 = f4fma(a0, w1.x, f1); a1 = f4fma(a1, w1.y, f1);
        a2 = f4fma(a2, w1.z, f1); a3 = f4fma(a3, w1.w, f1);
        a0 = f4fma(a0, w2.x, f2); a1 = f4fma(a1, w2.y, f2);
        a2 = f4fma(a2, w2.z, f2); a3 = f4fma(a3, w2.w, f2);
        a0 = f4fma(a0, w3.x, f3); a1 = f4fma(a1, w3.y, f3);
        a2 = f4fma(a2, w3.z, f3); a3 = f4fma(a3, w3.w, f3);
      }
      for (int j = nl + grp; j < deg; j += 2){   // LDS overflow fallback (essentially never)
        int s = csr[beg+j];
        float4 e = f4leaky(f4add(*(const float4*)(D + (size_t)s*8), ed));
        float4 w = f4expf(e);
        float4 f0 = fp8x4_f4(*(const unsigned int*)(H8 + ((size_t)s << 6) + c0b));
        a0 = f4fma(a0, w.x, f0); a1 = f4fma(a1, w.y, f0);
        a2 = f4fma(a2, w.z, f0); a3 = f4fma(a3, w.w, f0);
      }
      // cross-group reduce (lane stride 16, stays within half-wave)
      a0.x += __shfl_xor(a0.x, 16); a0.y += __shfl_xor(a0.y, 16); a0.z += __shfl_xor(a0.z, 16); a0.w += __shfl_xor(a0.w, 16);
      a1.x += __shfl_xor(a1.x, 16); a1.y += __shfl_xor(a1.y, 16); a1.z += __shfl_xor(a1.z, 16); a1.w += __shfl_xor(a1.w, 16);
      a2.x += __shfl_xor(a2.x, 16); a2.y += __shfl_xor(a2.y, 16); a2.z += __shfl_xor(a2.z, 16); a2.w += __shfl_xor(a2.w, 16);
      a3.x += __shfl_xor(a3.x, 16); a3.y += __shfl_xor(a3.y, 16); a3.z += __shfl_xor(a3.z, 16); a3.w += __shfl_xor(a3.w, 16);
      if (grp == 0){
        float4 fs = fp8x4_f4(*(const unsigned int*)(H8 + ((size_t)node << 6) + c0b));   // self term
        a0 = f4fma(a0, wself.x, fs);
        a1 = f4fma(a1, wself.y, fs);
        a2 = f4fma(a2, wself.z, fs);
        a3 = f4fma(a3, wself.w, fs);
        a0 = f4scale(a0, 1.f/(z4.x + 1e-16f));
        a1 = f4scale(a1, 1.f/(z4.y + 1e-16f));
        a2 = f4scale(a2, 1.f/(z4.z + 1e-16f));
        a3 = f4scale(a3, 1.f/(z4.w + 1e-16f));
        // Y row -> LDS (head-major, bf16, same rounding as before)
        unsigned short* yp = &ytile[lrow32][sub << 2];
        *(ushort4*)(yp)       = f2bf4(a0);
        *(ushort4*)(yp + 64)  = f2bf4(a1);
        *(ushort4*)(yp + 128) = f2bf4(a2);
        *(ushort4*)(yp + 192) = f2bf4(a3);
      }
    } else if (grp == 0){
      ushort4 z = make_ushort4(0,0,0,0);
      unsigned short* yp = &ytile[lrow32][sub << 2];
      *(ushort4*)(yp)       = z;
      *(ushort4*)(yp + 64)  = z;
      *(ushort4*)(yp + 128) = z;
      *(ushort4*)(yp + 192) = z;
    }
  }
  __syncthreads();      // ytile complete; wl/sl dead from here (gtile aliases them)
  // ---- GEMM phase over this block's 32 node-rows (two full 16-row MFMA tiles) ----
  int wv = tid >> 6, l = tid & 63;
  int lrow = l & 15;
  int lk = (l >> 4) << 3;
  int rbase4 = (l >> 4) << 2;         // 0,4,8,12
  // stage-A: G = relu(ytile@Wg + bg); wave wv owns head wv (col-chunks cc = wv*4..wv*4+3)
  bf16x8 afA[2][2];                   // [tile][kb]
  #pragma unroll
  for (int t = 0; t < 2; ++t){
    afA[t][0] = *(const bf16x8*)&ytile[t*16 + lrow][wv*64 + lk];
    afA[t][1] = *(const bf16x8*)&ytile[t*16 + lrow][wv*64 + 32 + lk];
  }
  #pragma unroll
  for (int q = 0; q < 4; ++q){
    int cc = wv*4 + q;
    bf16x8 b0 = *(const bf16x8*)&WT1[((size_t)((0*16 + cc)*64 + l))*8];
    bf16x8 b1 = *(const bf16x8*)&WT1[((size_t)((1*16 + cc)*64 + l))*8];
    int c = cc*16 + lrow;
    float bv = bg[c];
    #pragma unroll
    for (int t = 0; t < 2; ++t){
      f32x4 acc = {0.f, 0.f, 0.f, 0.f};
      acc = __builtin_amdgcn_mfma_f32_16x16x32_bf16(afA[t][0], b0, acc, 0, 0, 0);
      acc = __builtin_amdgcn_mfma_f32_16x16x32_bf16(afA[t][1], b1, acc, 0, 0, 0);
      #pragma unroll
      for (int r = 0; r < 4; ++r)
        gtile[(t*16 + rbase4 + r)*264 + c] = f2bf(fmaxf(acc[r] + bv, 0.f));
    }
  }
  __syncthreads();      // gtile complete (cross-wave columns)
  // stage-B: [P8|R] = G @ [Wl|Wr]; wave wv owns cc = wv*2, wv*2+1; B-frags shared across tiles
  bf16x8 afb[2][8];
  #pragma unroll
  for (int t = 0; t < 2; ++t)
    #pragma unroll
    for (int kb = 0; kb < 8; ++kb)
      afb[t][kb] = *(const bf16x8*)&gtile[(t*16 + lrow)*264 + kb*32 + lk];
  #pragma unroll
  for (int q = 0; q < 2; ++q){
    int cc = wv*2 + q;
    f32x4 acc0 = {0.f, 0.f, 0.f, 0.f};
    f32x4 acc1 = {0.f, 0.f, 0.f, 0.f};
    #pragma unroll
    for (int kb = 0; kb < 8; ++kb){
      bf16x8 b = *(const bf16x8*)&WT2[((size_t)((kb*8 + cc)*64 + l))*8];
      acc0 = __builtin_amdgcn_mfma_f32_16x16x32_bf16(afb[0][kb], b, acc0, 0, 0, 0);
      acc1 = __builtin_amdgcn_mfma_f32_16x16x32_bf16(afb[1][kb], b, acc1, 0, 0, 0);
    }
    int c = cc*16 + lrow;
    #pragma unroll
    for (int t = 0; t < 2; ++t){
      const f32x4& acc = t ? acc1 : acc0;
      #pragma unroll
      for (int r = 0; r < 4; ++r){
        int nd = blockIdx.x*32 + t*16 + rbase4 + r;
        if (nd < n){
          float v = acc[r];
          if (c < 64) P8[(size_t)nd*64 + c] = f2fp8(v);
          else        R[(size_t)nd*64 + (c - 64)] = f2bf(v);
        }
      }
    }
  }
}

// ---------- SAGE aggregation + fused edge-MLP GEMM epilogue ----------
// Gather loop 4-deep (4 rows in flight); chain order preserved. W1 frags from L2-resident WT3.
__global__ __launch_bounds__(256) void k_sage(const unsigned char* __restrict__ P8, const unsigned short* __restrict__ R,
                                              const float* __restrict__ b, const int* __restrict__ offs,
                                              const int* __restrict__ csr, const unsigned short* __restrict__ WT3,
                                              unsigned char* __restrict__ T2, int n){
  __shared__ unsigned short stile[16][72];     // 16 S rows bf16, pad 72 (144 B stride)
  int tid = threadIdx.x;
  int wv = tid >> 6, l = tid & 63;
  int base = blockIdx.x*16;
  int lrow16 = (wv << 2) + (l >> 4);           // block-local row 0..15
  int node = base + lrow16;
  int l15 = l & 15;
  int grp = l15 >> 3, sub = l15 & 7;
  bool ok = node < n;
  int beg = 0, end = 0;
  if (ok){ beg = offs[node]; end = offs[node+1]; }
  float4 aL0 = f4s(0.f), aH0 = f4s(0.f), aL1 = f4s(0.f), aH1 = f4s(0.f);
  int i = beg + grp;
  for (; i + 6 < end; i += 8){
    int s0 = csr[i], s1 = csr[i+2], s2 = csr[i+4], s3 = csr[i+6];
    uint2 u0 = *(const uint2*)(P8 + (size_t)s0*64 + (sub<<3));
    uint2 u1 = *(const uint2*)(P8 + (size_t)s1*64 + (sub<<3));
    uint2 u2 = *(const uint2*)(P8 + (size_t)s2*64 + (sub<<3));
    uint2 u3 = *(const uint2*)(P8 + (size_t)s3*64 + (sub<<3));
    aL0 = f4add(aL0, fp8x4_f4(u0.x)); aH0 = f4add(aH0, fp8x4_f4(u0.y));
    aL1 = f4add(aL1, fp8x4_f4(u1.x)); aH1 = f4add(aH1, fp8x4_f4(u1.y));
    aL0 = f4add(aL0, fp8x4_f4(u2.x)); aH0 = f4add(aH0, fp8x4_f4(u2.y));
    aL1 = f4add(aL1, fp8x4_f4(u3.x)); aH1 = f4add(aH1, fp8x4_f4(u3.y));
  }
  for (; i + 2 < end; i += 4){
    int s0 = csr[i], s1 = csr[i+2];
    uint2 u0 = *(const uint2*)(P8 + (size_t)s0*64 + (sub<<3));
    uint2 u1 = *(const uint2*)(P8 + (size_t)s1*64 + (sub<<3));
    aL0 = f4add(aL0, fp8x4_f4(u0.x)); aH0 = f4add(aH0, fp8x4_f4(u0.y));
    aL1 = f4add(aL1, fp8x4_f4(u1.x)); aH1 = f4add(aH1, fp8x4_f4(u1.y));
  }
  if (i < end){
    int s0 = csr[i];
    uint2 u0 = *(const uint2*)(P8 + (size_t)s0*64 + (sub<<3));
    aL0 = f4add(aL0, fp8x4_f4(u0.x)); aH0 = f4add(aH0, fp8x4_f4(u0.y));
  }
  float4 aL = f4add(aL0, aL1), aH = f4add(aH0, aH1);
  red2(aL, aH);
  float4 r0 = f4s(0.f), r1 = f4s(0.f);
  if (ok){
    float minv = 1.f / fmaxf((float)(end - beg), 1.f);
    uint4 ur = *(const uint4*)(R + (size_t)node*64 + (sub<<3));
    float4 b0 = *(const float4*)(b + (sub<<3));
    float4 b1 = *(const float4*)(b + (sub<<3) + 4);
    r0 = f4relu(f4add(f4fma(b0, minv, aL), bfu2f4_lo(ur)));
    r1 = f4relu(f4add(f4fma(b1, minv, aH), bfu2f4_hi(ur)));
  }
  if (grp == 0) *(u16x8*)&stile[lrow16][sub << 3] = f2bf8(r0, r1);
  __syncthreads();
  // MFMA epilogue: 16 rows x 128 cols, K=64; waves split the 8 col-chunks (2 each)
  int lrow = l & 15, lk = (l >> 4) << 3;
  bf16x8 af0 = *(const bf16x8*)&stile[lrow][lk];
  bf16x8 af1 = *(const bf16x8*)&stile[lrow][32 + lk];
  int rbase = (l >> 4) << 2;
  #pragma unroll
  for (int q = 0; q < 2; ++q){
    int cc = wv*2 + q;
    f32x4 acc = {0.f, 0.f, 0.f, 0.f};
    acc = __builtin_amdgcn_mfma_f32_16x16x32_bf16(af0, *(const bf16x8*)&WT3[((size_t)((0*8 + cc)*64 + l))*8], acc, 0, 0, 0);
    acc = __builtin_amdgcn_mfma_f32_16x16x32_bf16(af1, *(const bf16x8*)&WT3[((size_t)((1*8 + cc)*64 + l))*8], acc, 0, 0, 0);
    int c = cc*16 + lrow;
    #pragma unroll
    for (int r = 0; r < 4; ++r){
      int nd = base + rbase + r;
      if (nd < n) T2[(size_t)nd*128 + c] = f2fp8(acc[r]);
    }
  }
}

// ---------- edge MLP, edge-order: 8 lanes/edge; T2 = [U|V] fp8 rows of 128 B ----------
__global__ __launch_bounds__(256) void k_mlp(const unsigned char* __restrict__ T2,
                                             const float* __restrict__ b1, const float* __restrict__ W2,
                                             const float* __restrict__ b2, const int* __restrict__ src,
                                             const int* __restrict__ dst, float* __restrict__ out, int E){
  int t = threadIdx.x;
  int e = blockIdx.x*32 + (t >> 3);
  if (e >= E) return;
  int sub = t & 7;
  int s = src[e], d = dst[e];
  uint2 uu = *(const uint2*)(T2 + (size_t)s*128 + (sub<<3));        // 8 fp8 of U[s]
  uint2 vv = *(const uint2*)(T2 + (size_t)d*128 + 64 + (sub<<3));   // 8 fp8 of V[d]
  float4 u0 = fp8x4_f4(uu.x), u1 = fp8x4_f4(uu.y);
  float4 v0 = fp8x4_f4(vv.x), v1 = fp8x4_f4(vv.y);
  float4 bb0 = *(const float4*)(b1 + (sub<<3));
  float4 bb1 = *(const float4*)(b1 + (sub<<3) + 4);
  float4 w0 = *(const float4*)(W2 + (sub<<3));
  float4 w1 = *(const float4*)(W2 + (sub<<3) + 4);
  float4 ta = f4relu(f4add(f4add(u0, v0), bb0));
  float4 tb = f4relu(f4add(f4add(u1, v1), bb1));
  float p = ta.x*w0.x + ta.y*w0.y + ta.z*w0.z + ta.w*w0.w
          + tb.x*w1.x + tb.y*w1.y + tb.z*w1.z + tb.w*w1.w;
  p += __shfl_xor(p, 1);
  p += __shfl_xor(p, 2);
  p += __shfl_xor(p, 4);
  if (sub == 0) out[e] = 1.f / (1.f + __expf(-(p + b2[0])));
}

extern "C" void kernel_launch(void* const* d_in, const int* in_sizes, int n_in,
                              void* d_out, int out_size, void* d_ws, size_t ws_size,
                              hipStream_t stream){
  const float* x     = (const float*)d_in[0];
  const int*   eidx  = (const int*)  d_in[1];
  const float* W_gcn = (const float*)d_in[2];
  const float* b_gcn = (const float*)d_in[3];
  const float* W_gat = (const float*)d_in[4];
  const float* att_s = (const float*)d_in[5];
  const float* att_d = (const float*)d_in[6];
  const float* b_gat = (const float*)d_in[7];
  const float* W_sl  = (const float*)d_in[8];
  const float* b_sg  = (const float*)d_in[9];
  const float* W_sr  = (const float*)d_in[10];
  const float* W1    = (const float*)d_in[11];
  const float* b1    = (const float*)d_in[12];
  const float* W2    = (const float*)d_in[13];
  const float* b2    = (const float*)d_in[14];
  float* out = (float*)d_out;

  const int N = in_sizes[0] / 128;
  const int E = in_sizes[1] / 2;
  const int* src = eidx;
  const int* dst = eidx + E;

  // ---- workspace layout: f32, then bf16, then fp8, then int ----
  float* ws   = (float*)d_ws;
  float* dinv = ws;                        // N
  float* D    = dinv + (size_t)N;          // N*8  (a_s | a_d)
  float* Vs   = D + (size_t)N*8;           // 256
  float* Vd   = Vs + 256;                  // 256
  unsigned short* WT = (unsigned short*)(Vd + 256);        // 7168*8 bf16 weight frag tables (112 KB)
  unsigned short* R  = WT + (size_t)7168*8;// N*64  bf16 (SAGE root term, compact)
  unsigned char*  A8 = (unsigned char*)(R + (size_t)N*64); // N*64  fp8 (dinv * x @ W_gcn)
  unsigned char*  H8 = A8 + (size_t)N*64;  // N*64  fp8 (GCN out shadow)
  unsigned char*  P8 = H8 + (size_t)N*64;  // N*64  fp8 (SAGE neighbor term, compact)
  unsigned char*  T2 = P8 + (size_t)N*64;  // N*128 fp8 (U | V)
  int* cnt  = (int*)(T2 + (size_t)N*128);  // N
  int* excl = cnt + N;                     // N
  int* bsum = excl + N;                    // 256
  int* offs = bsum + 256;                  // N+1
  int* rank = offs + N + 1;                // E
  int* csr  = rank + E;                    // E

  const int nb = (N + 255) / 256;
  const int fb = (E + 255) / 256;
  const int gtiles = (N + 63) / 64;
  const int nwb = (N + 15) / 16;          // 4 nodes/wave kernels (16 nodes/block)

  // ---- CSR build (+ packed independent work: WT frag tables, Vs/Vd basis, GCN GEMM) ----
  hipMemsetAsync(cnt, 0, (size_t)N*sizeof(int), stream);
  k_rankw <<<fb + 28, 256, 0, stream>>>(dst, cnt, rank, E, fb, W_gat, W_sl, W_sr,
                                        W1, W1 + 64*64, WT);
  k_scan1v<<<nb + 1, 256, 0, stream>>>(cnt, excl, bsum, N, nb, W_gat, att_s, att_d, Vs, Vd);
  k_scan3b<<<nb, 256, 0, stream>>>(cnt, excl, bsum, offs, dinv, N, E, nb);
  k_fillg <<<fb + gtiles, 256, 0, stream>>>(src, dst, offs, rank, csr, E, fb,
                                            x, W_gcn, A8, N, dinv);

  // ---- GCN aggregation: H8 = relu(...); D = GAT logits (fused epilogue) ----
  k_gcn <<<nwb, 256, 0, stream>>>(A8, dinv, b_gcn, offs, csr, Vs, Vd, H8, D, N);

  // ---- GAT softmax + aggregation + GAT-GEMM + SAGE-GEMM fused (32 nodes/block): -> [P8 | R] ----
  k_gat2f<<<(N+31)/32, 256, 0, stream>>>(D, H8, offs, csr, WT, b_gat, R, P8, N);

  // ---- SAGE + edge GEMM fused: S = relu(mean(P8[src]) + b + R); T2 = fp8(S @ WT3) ----
  k_sage<<<nwb, 256, 0, stream>>>(P8, R, b_sg, offs, csr, WT + (size_t)6144*8, T2, N);

  // ---- edge MLP: edge-order eval, coalesced out ----
  k_mlp <<<(E+31)/32, 256, 0, stream>>>(T2, b1, W2, b2, src, dst, out, E);
}

// Round 11
// 264.540 us; speedup vs baseline: 1.0581x; 1.0003x over previous
//
#include <hip/hip_runtime.h>
#include <math.h>

// ---------- float4 / bf16 / fp8 helpers ----------
typedef float v2f __attribute__((ext_vector_type(2)));
static __device__ __forceinline__ float4 f4s(float v){ return make_float4(v,v,v,v); }
static __device__ __forceinline__ float4 f4add(float4 a, float4 b){ return make_float4(a.x+b.x,a.y+b.y,a.z+b.z,a.w+b.w); }
static __device__ __forceinline__ float4 f4max(float4 a, float4 b){ return make_float4(fmaxf(a.x,b.x),fmaxf(a.y,b.y),fmaxf(a.z,b.z),fmaxf(a.w,b.w)); }
static __device__ __forceinline__ float4 f4scale(float4 a, float s){ return make_float4(a.x*s,a.y*s,a.z*s,a.w*s); }
static __device__ __forceinline__ float4 f4fma(float4 acc, float s, float4 b){
  acc.x += s*b.x; acc.y += s*b.y; acc.z += s*b.z; acc.w += s*b.w; return acc;
}
static __device__ __forceinline__ float4 f4relu(float4 a){ return f4max(a, f4s(0.f)); }
static __device__ __forceinline__ float4 f4leaky(float4 a){
  return make_float4(a.x>0.f?a.x:0.2f*a.x, a.y>0.f?a.y:0.2f*a.y, a.z>0.f?a.z:0.2f*a.z, a.w>0.f?a.w:0.2f*a.w);
}
static __device__ __forceinline__ float4 f4expf(float4 a){ return make_float4(__expf(a.x),__expf(a.y),__expf(a.z),__expf(a.w)); }
static __device__ __forceinline__ unsigned short f2bf(float f){
  unsigned int u = __float_as_uint(f);
  unsigned int r = (u + 0x7fffu + ((u >> 16) & 1u)) >> 16;
  return (unsigned short)r;
}
static __device__ __forceinline__ ushort4 f2bf4(float4 f){
  ushort4 r; r.x=f2bf(f.x); r.y=f2bf(f.y); r.z=f2bf(f.z); r.w=f2bf(f.w); return r;
}
// bf16x4 (as uint2) -> float4 : 4 VALU ops
static __device__ __forceinline__ float4 bfu2f4(uint2 u){
  return make_float4(__uint_as_float(u.x << 16), __uint_as_float(u.x & 0xffff0000u),
                     __uint_as_float(u.y << 16), __uint_as_float(u.y & 0xffff0000u));
}
static __device__ __forceinline__ float4 bfu2f4_lo(uint4 u){ return bfu2f4(make_uint2(u.x, u.y)); }
static __device__ __forceinline__ float4 bfu2f4_hi(uint4 u){ return bfu2f4(make_uint2(u.z, u.w)); }

typedef __attribute__((ext_vector_type(8))) unsigned short u16x8;
static __device__ __forceinline__ u16x8 f2bf8(float4 a, float4 b){
  u16x8 r;
  r[0]=f2bf(a.x); r[1]=f2bf(a.y); r[2]=f2bf(a.z); r[3]=f2bf(a.w);
  r[4]=f2bf(b.x); r[5]=f2bf(b.y); r[6]=f2bf(b.z); r[7]=f2bf(b.w);
  return r;
}
// reduce two float4 across 2 groups at lane stride 8
static __device__ __forceinline__ void red2(float4& a, float4& b){
  a.x += __shfl_xor(a.x, 8); a.y += __shfl_xor(a.y, 8);
  a.z += __shfl_xor(a.z, 8); a.w += __shfl_xor(a.w, 8);
  b.x += __shfl_xor(b.x, 8); b.y += __shfl_xor(b.y, 8);
  b.z += __shfl_xor(b.z, 8); b.w += __shfl_xor(b.w, 8);
}
// fp8 (OCP e4m3) pack/unpack
static __device__ __forceinline__ unsigned char f2fp8(float v){
  return (unsigned char)(__builtin_amdgcn_cvt_pk_fp8_f32(v, v, 0, false) & 0xff);
}
static __device__ __forceinline__ unsigned int f4_fp8x4(float4 v){
  unsigned int r = __builtin_amdgcn_cvt_pk_fp8_f32(v.x, v.y, 0, false);
  r = __builtin_amdgcn_cvt_pk_fp8_f32(v.z, v.w, r, true);
  return r;
}
static __device__ __forceinline__ float4 fp8x4_f4(unsigned int q){
  v2f lo = __builtin_amdgcn_cvt_pk_f32_fp8(q, false);
  v2f hi = __builtin_amdgcn_cvt_pk_f32_fp8(q, true);
  return make_float4(lo[0], lo[1], hi[0], hi[1]);
}
static __device__ __forceinline__ float dot8(float4 a, float4 b, const float* v){
  return a.x*v[0]+a.y*v[1]+a.z*v[2]+a.w*v[3]+b.x*v[4]+b.y*v[5]+b.z*v[6]+b.w*v[7];
}

// ---------- MFMA types ----------
typedef __attribute__((ext_vector_type(8))) short bf16x8;   // 8 bf16 = 4 VGPRs
typedef __attribute__((ext_vector_type(4))) float f32x4;

// ---------- CSR rank + (packed) bf16 weight-fragment table precompute ----------
// blocks [0, fb): rank.  blocks [fb, fb+28): WT fill (7168 slots).
// WT1 = slots [0,2048): W_gat frags (H4 layout, ld 256).
// WT2 = slots [2048,6144): [W_sl|W_sr] frags (ld 64, col split at 64).
// WT3 = slots [6144,7168): [W1top|W1bot] frags (ld 64, col split at 64).
__global__ __launch_bounds__(256) void k_rankw(const int* __restrict__ dst, int* __restrict__ cnt,
                                               int* __restrict__ rank, int E, int fb,
                                               const float* __restrict__ Wg, const float* __restrict__ Wl,
                                               const float* __restrict__ Wr, const float* __restrict__ W1a,
                                               const float* __restrict__ W1b, unsigned short* __restrict__ WT){
  if ((int)blockIdx.x < fb){
    int t = blockIdx.x*256 + threadIdx.x;
    if (t < E) rank[t] = atomicAdd(&cnt[dst[t]], 1);
    return;
  }
  int s = (blockIdx.x - fb)*256 + threadIdx.x;     // 0..7167
  int l = s & 63, f = s >> 6;
  const float* wp; int ld;
  if (s < 2048){
    int cc = f & 15, kb = f >> 4;
    int c  = cc*16 + (l & 15);
    int kr = kb*32 + ((l >> 4) << 3);
    wp = Wg + (size_t)kr*256 + c; ld = 256;
  } else if (s < 6144){
    int f2 = f - 32;
    int cc = f2 & 7, kb = f2 >> 3;
    int c  = cc*16 + (l & 15);
    int kr = kb*32 + ((l >> 4) << 3);
    wp = (c >= 64) ? (Wr + (size_t)kr*64 + (c - 64)) : (Wl + (size_t)kr*64 + c);
    ld = 64;
  } else {
    int f3 = f - 96;
    int cc = f3 & 7, kb = f3 >> 3;
    int c  = cc*16 + (l & 15);
    int kr = kb*32 + ((l >> 4) << 3);
    wp = (c >= 64) ? (W1b + (size_t)kr*64 + (c - 64)) : (W1a + (size_t)kr*64 + c);
    ld = 64;
  }
  u16x8 o;
  #pragma unroll
  for (int j = 0; j < 8; ++j) o[j] = f2bf(wp[(size_t)j*ld]);
  *(u16x8*)(WT + (size_t)s*8) = o;
}

// scan1 (blocks [0,nb)) + GAT attention basis vectors Vs/Vd (block nb, independent work packed in)
__global__ __launch_bounds__(256) void k_scan1v(const int* __restrict__ cnt, int* __restrict__ excl,
                                                int* __restrict__ bsum, int n, int nb,
                                                const float* __restrict__ Wg, const float* __restrict__ as,
                                                const float* __restrict__ ad, float* __restrict__ Vs,
                                                float* __restrict__ Vd){
  if ((int)blockIdx.x == nb){
    int t = threadIdx.x;
    int h = t >> 6, k = t & 63;
    float s = 0.f, d = 0.f;
    const float* wr = Wg + (size_t)k*256 + h*64;
    const float* ar = as + h*64;
    const float* dr = ad + h*64;
    for (int c = 0; c < 64; ++c){ float w = wr[c]; s += w*ar[c]; d += w*dr[c]; }
    Vs[t] = s; Vd[t] = d;
    return;
  }
  __shared__ int sc[256];
  int t = threadIdx.x; int i = blockIdx.x*256 + t;
  int v = (i<n)?cnt[i]:0;
  sc[t]=v; __syncthreads();
  for (int o=1;o<256;o<<=1){ int a=(t>=o)?sc[t-o]:0; __syncthreads(); sc[t]+=a; __syncthreads(); }
  if (i<n) excl[i] = sc[t]-v;
  if (t==255) bsum[blockIdx.x] = sc[t];
}
// scan3 with per-block redundant in-LDS scan of bsum
__global__ __launch_bounds__(256) void k_scan3b(const int* __restrict__ cnt, const int* __restrict__ excl,
                                                const int* __restrict__ bsum, int* __restrict__ offs,
                                                float* __restrict__ dinv, int n, int E, int nb){
  __shared__ int sb[256];
  int t = threadIdx.x;
  int v = (t<nb)?bsum[t]:0;
  sb[t]=v; __syncthreads();
  for (int o=1;o<256;o<<=1){ int a=(t>=o)?sb[t-o]:0; __syncthreads(); sb[t]+=a; __syncthreads(); }
  int bex = sb[blockIdx.x] - bsum[blockIdx.x];     // exclusive prefix for this block
  int i = blockIdx.x*256 + t;
  if (i < n){
    offs[i] = excl[i] + bex;
    dinv[i] = rsqrtf((float)cnt[i] + 1.0f);   // deg includes self-loop
    if (i == 0) offs[n] = E;
  }
}

// ---------- fused CSR-fill + GCN GEMM (independent work, one dispatch) ----------
// blocks [0, fb): csr scatter-fill.  blocks [fb, fb+gtiles): A8 = fp8(dinv * (x @ W_gcn)).
__global__ __launch_bounds__(256) void k_fillg(const int* __restrict__ src, const int* __restrict__ dstv,
                                               const int* __restrict__ offs, const int* __restrict__ rank,
                                               int* __restrict__ csr, int E, int fb,
                                               const float* __restrict__ x, const float* __restrict__ Wg,
                                               unsigned char* __restrict__ a8, int n,
                                               const float* __restrict__ dinv){
  if ((int)blockIdx.x < fb){
    int t = blockIdx.x*256 + threadIdx.x;
    if (t < E) csr[offs[dstv[t]] + rank[t]] = src[t];
    return;
  }
  // ---- GCN GEMM: K=128 (KB=4), Cout=64 (CC=4), f32 in, fp8 out, rowscale=dinv ----
  __shared__ unsigned short wb[1024*8];        // 16 KB weight frags
  int tid = threadIdx.x;
  for (int s = tid; s < 1024; s += 256){
    int l = s & 63, f = s >> 6;
    int cc = f & 3, kb = f >> 2;
    int c  = cc*16 + (l & 15);
    int kr = kb*32 + ((l >> 4) << 3);
    const float* wp = Wg + (size_t)kr*64 + c;
    unsigned short* dp = &wb[s*8];
    #pragma unroll
    for (int j = 0; j < 8; ++j) dp[j] = f2bf(wp[(size_t)j*64]);
  }
  __syncthreads();
  int wv = tid >> 6, l = tid & 63;
  int lrow = l & 15;
  int lk = (l >> 4) << 3;
  int g = blockIdx.x - fb;                     // exactly one 64-row group per block
  int r0 = (g << 6) + (wv << 4);
  int m = r0 + lrow;
  bf16x8 afr[4];
  #pragma unroll
  for (int kb = 0; kb < 4; ++kb){
    bf16x8 a = {0,0,0,0,0,0,0,0};
    if (m < n){
      const float* p = x + (size_t)m*128 + kb*32 + lk;
      float4 f0 = *(const float4*)p;
      float4 f1 = *(const float4*)(p + 4);
      a[0]=(short)f2bf(f0.x); a[1]=(short)f2bf(f0.y); a[2]=(short)f2bf(f0.z); a[3]=(short)f2bf(f0.w);
      a[4]=(short)f2bf(f1.x); a[5]=(short)f2bf(f1.y); a[6]=(short)f2bf(f1.z); a[7]=(short)f2bf(f1.w);
    }
    afr[kb] = a;
  }
  int rbase = r0 + ((l >> 4) << 2);
  float sc[4];
  #pragma unroll
  for (int r = 0; r < 4; ++r) sc[r] = (rbase + r < n) ? dinv[rbase + r] : 0.f;
  #pragma unroll
  for (int cc = 0; cc < 4; ++cc){
    f32x4 acc = {0.f, 0.f, 0.f, 0.f};
    #pragma unroll
    for (int kb = 0; kb < 4; ++kb){
      bf16x8 b = *(const bf16x8*)&wb[((kb*4 + cc)*64 + l)*8];
      acc = __builtin_amdgcn_mfma_f32_16x16x32_bf16(afr[kb], b, acc, 0, 0, 0);
    }
    int c = cc*16 + lrow;
    #pragma unroll
    for (int r = 0; r < 4; ++r){
      int rr = rbase + r;
      if (rr < n) a8[(size_t)rr*64 + c] = f2fp8(acc[r] * sc[r]);
    }
  }
}

// ---------- GCN aggregation + fused GAT-logit epilogue ----------
// Gather loop 4-deep (4 rows in flight); per-chain accumulation order identical to 2-deep.
__global__ __launch_bounds__(256) void k_gcn(const unsigned char* __restrict__ a8, const float* __restrict__ dinv,
                                             const float* __restrict__ b, const int* __restrict__ offs,
                                             const int* __restrict__ csr, const float* __restrict__ Vs,
                                             const float* __restrict__ Vd, unsigned char* __restrict__ h8,
                                             float* __restrict__ D, int n){
  __shared__ float svs[256], svd[256];
  svs[threadIdx.x] = Vs[threadIdx.x];
  svd[threadIdx.x] = Vd[threadIdx.x];
  __syncthreads();
  int l = threadIdx.x & 63;
  int node = (((blockIdx.x*256 + threadIdx.x) >> 6) << 2) + (l >> 4);
  int l15 = l & 15;
  int grp = l15 >> 3, sub = l15 & 7;
  bool ok = node < n;
  int beg = 0, end = 0;
  float di = 0.f;
  if (ok){ beg = offs[node]; end = offs[node+1]; di = dinv[node]; }
  float4 aL0 = f4s(0.f), aH0 = f4s(0.f), aL1 = f4s(0.f), aH1 = f4s(0.f);
  int i = beg + grp;
  for (; i + 6 < end; i += 8){
    int s0 = csr[i], s1 = csr[i+2], s2 = csr[i+4], s3 = csr[i+6];
    uint2 u0 = *(const uint2*)(a8 + (size_t)s0*64 + (sub<<3));
    uint2 u1 = *(const uint2*)(a8 + (size_t)s1*64 + (sub<<3));
    uint2 u2 = *(const uint2*)(a8 + (size_t)s2*64 + (sub<<3));
    uint2 u3 = *(const uint2*)(a8 + (size_t)s3*64 + (sub<<3));
    aL0 = f4add(aL0, fp8x4_f4(u0.x)); aH0 = f4add(aH0, fp8x4_f4(u0.y));
    aL1 = f4add(aL1, fp8x4_f4(u1.x)); aH1 = f4add(aH1, fp8x4_f4(u1.y));
    aL0 = f4add(aL0, fp8x4_f4(u2.x)); aH0 = f4add(aH0, fp8x4_f4(u2.y));
    aL1 = f4add(aL1, fp8x4_f4(u3.x)); aH1 = f4add(aH1, fp8x4_f4(u3.y));
  }
  for (; i + 2 < end; i += 4){
    int s0 = csr[i], s1 = csr[i+2];
    uint2 u0 = *(const uint2*)(a8 + (size_t)s0*64 + (sub<<3));
    uint2 u1 = *(const uint2*)(a8 + (size_t)s1*64 + (sub<<3));
    aL0 = f4add(aL0, fp8x4_f4(u0.x)); aH0 = f4add(aH0, fp8x4_f4(u0.y));
    aL1 = f4add(aL1, fp8x4_f4(u1.x)); aH1 = f4add(aH1, fp8x4_f4(u1.y));
  }
  if (i < end){
    int s0 = csr[i];
    uint2 u0 = *(const uint2*)(a8 + (size_t)s0*64 + (sub<<3));
    aL0 = f4add(aL0, fp8x4_f4(u0.x)); aH0 = f4add(aH0, fp8x4_f4(u0.y));
  }
  float4 aL = f4add(aL0, aL1), aH = f4add(aH0, aH1);
  red2(aL, aH);
  if (ok){
    uint2 us = *(const uint2*)(a8 + (size_t)node*64 + (sub<<3));   // self (pre-scaled)
    aL = f4add(aL, fp8x4_f4(us.x)); aH = f4add(aH, fp8x4_f4(us.y));
    float4 b0 = *(const float4*)(b + (sub<<3));
    float4 b1 = *(const float4*)(b + (sub<<3) + 4);
    float4 r0 = f4relu(f4fma(b0, di, aL));                          // both groups compute H slice
    float4 r1 = f4relu(f4fma(b1, di, aH));
    if (grp == 0){
      uint2 q; q.x = f4_fp8x4(r0); q.y = f4_fp8x4(r1);
      *(uint2*)(h8 + (size_t)node*64 + (sub<<3)) = q;
    }
    // GAT logits: this group's two heads
    const float* vs0 = svs + (grp*128) + (sub<<3);   // head grp*2   (h*64 stride)
    const float* vd0 = svd + (grp*128) + (sub<<3);
    float s0 = dot8(r0, r1, vs0);
    float s1 = dot8(r0, r1, vs0 + 64);
    float d0 = dot8(r0, r1, vd0);
    float d1 = dot8(r0, r1, vd0 + 64);
    #pragma unroll
    for (int o = 1; o < 8; o <<= 1){                 // 8-lane cluster reduce (ok uniform per cluster)
      s0 += __shfl_xor(s0, o); s1 += __shfl_xor(s1, o);
      d0 += __shfl_xor(d0, o); d1 += __shfl_xor(d1, o);
    }
    if (sub == 0){
      *(float2*)(D + (size_t)node*8 + grp*2)     = make_float2(s0, s1);
      *(float2*)(D + (size_t)node*8 + 4 + grp*2) = make_float2(d0, d1);
    }
  }
}

// ---------- fused GAT softmax + aggregation + GAT-GEMM + SAGE-GEMM (32 nodes/block) ----------
// Softmax phase: 4 sequential batches of 8 nodes (wl/sl per-half-wave private -> no intra-loop
// barriers), filling a 32x264 bf16 ytile.  Then one GEMM phase over two FULL 16-row MFMA tiles:
// stage-A G = relu(ytile@Wg + bg) -> gtile (aliases dead wl/sl), stage-B [P8|R] = G @ [Wl|Wr].
#define GAT_CAP 128
__global__ __launch_bounds__(256) void k_gat2f(const float* __restrict__ D, const unsigned char* __restrict__ H8,
                                               const int* __restrict__ offs, const int* __restrict__ csr,
                                               const unsigned short* __restrict__ WT, const float* __restrict__ bg,
                                               unsigned short* __restrict__ R, unsigned char* __restrict__ P8, int n){
  __shared__ __align__(16) unsigned char smem_raw[8*GAT_CAP*4*4 + 8*GAT_CAP*4];  // wl 16KB + sl 4KB
  __shared__ unsigned short ytile[32][264];                                       // 16.9 KB
  float (*wl)[GAT_CAP*4] = reinterpret_cast<float (*)[GAT_CAP*4]>(smem_raw);
  int   (*sl)[GAT_CAP]   = reinterpret_cast<int (*)[GAT_CAP]>(smem_raw + 8*GAT_CAP*4*4);
  unsigned short* gtile  = reinterpret_cast<unsigned short*>(smem_raw);           // 32x264 = 16.9KB alias
  const unsigned short* WT1 = WT;               // 2048 slots (W_gat frags)
  const unsigned short* WT2 = WT + 2048*8;      // 4096 slots ([Wl|Wr] frags)
  int tid = threadIdx.x;
  int hw = tid >> 5;                 // half-wave index in block (0..7)
  int l5 = tid & 31;
  int grp = l5 >> 4;
  int sub = l5 & 15;
  // ---- softmax + aggregation: 4 batches of 8 nodes ----
  for (int batch = 0; batch < 4; ++batch){
    int lrow32 = batch*8 + hw;                  // ytile row
    int node = blockIdx.x*32 + lrow32;
    if (node < n){
      int beg = offs[node], end = offs[node+1];
      int deg = end - beg;
      float4 ed  = *(const float4*)(D + (size_t)node*8 + 4);
      float4 es0 = *(const float4*)(D + (size_t)node*8);
      float4 wself = f4expf(f4leaky(f4add(es0, ed)));
      // phase A: per-edge exp weights + src byte-offset -> LDS (first GAT_CAP), z accumulation (all)
      float4 z4 = f4s(0.f);
      for (int i = beg + l5; i < end; i += 32){
        int s = csr[i];
        float4 w = f4expf(f4leaky(f4add(*(const float4*)(D + (size_t)s*8), ed)));
        int li = i - beg;
        if (li < GAT_CAP){ *(float4*)&wl[hw][li<<2] = w; sl[hw][li] = s << 6; }  // 64 B per H8 row
        z4 = f4add(z4, w);
      }
      for (int m = 1; m < 32; m <<= 1){
        z4.x += __shfl_xor(z4.x, m); z4.y += __shfl_xor(z4.y, m);
        z4.z += __shfl_xor(z4.z, m); z4.w += __shfl_xor(z4.w, m);
      }
      z4 = f4add(z4, wself);
      // phase C: 2 edge-groups x 16 lanes per node; lane covers 4 cols (4 B) of the 64-col H8 row
      int c0b = sub << 2;           // byte offset of 4-col fp8 slice
      float4 a0 = f4s(0.f), a1 = f4s(0.f), a2 = f4s(0.f), a3 = f4s(0.f);  // per-head accumulators
      int nl = deg < GAT_CAP ? deg : GAT_CAP;
      int i = grp;
      for (; i + 2 < nl; i += 4){
        int o0 = sl[hw][i], o1 = sl[hw][i+2];
        float4 w0 = *(const float4*)&wl[hw][i<<2];
        float4 w1 = *(const float4*)&wl[hw][(i+2)<<2];
        unsigned int q0 = *(const unsigned int*)(H8 + o0 + c0b);
        unsigned int q1 = *(const unsigned int*)(H8 + o1 + c0b);
        float4 f0 = fp8x4_f4(q0);
        float4 f1 = fp8x4_f4(q1);
        a0 = f4fma(a0, w0.x, f0); a1 = f4fma(a1, w0.y, f0);
        a2 = f4fma(a2, w0.z, f0); a3 = f4fma(a3, w0.w, f0);
        a0 = f4fma(a0, w1.x, f1); a1 = f4fma(a1, w1.y, f1);
        a2 = f4fma(a2, w1.z, f1); a3 = f4fma(a3, w1.w, f1);
      }
      if (i < nl){
        float4 w0 = *(const float4*)&wl[hw][i<<2];
        float4 f0 = fp8x4_f4(*(const unsigned int*)(H8 + sl[hw][i] + c0b));
        a0 = f4fma(a0, w0.x, f0); a1 = f4fma(a1, w0.y, f0);
        a2 = f4fma(a2, w0.z, f0); a3 = f4fma(a3, w0.w, f0);
      }
      for (int j = nl + grp; j < deg; j += 2){   // LDS overflow fallback (essentially never)
        int s = csr[beg+j];
        float4 e = f4leaky(f4add(*(const float4*)(D + (size_t)s*8), ed));
        float4 w = f4expf(e);
        float4 f0 = fp8x4_f4(*(const unsigned int*)(H8 + ((size_t)s << 6) + c0b));
        a0 = f4fma(a0, w.x, f0); a1 = f4fma(a1, w.y, f0);
        a2 = f4fma(a2, w.z, f0); a3 = f4fma(a3, w.w, f0);
      }
      // cross-group reduce (lane stride 16, stays within half-wave)
      a0.x += __shfl_xor(a0.x, 16); a0.y += __shfl_xor(a0.y, 16); a0.z += __shfl_xor(a0.z, 16); a0.w += __shfl_xor(a0.w, 16);
      a1.x += __shfl_xor(a1.x, 16); a1.y += __shfl_xor(a1.y, 16); a1.z += __shfl_xor(a1.z, 16); a1.w += __shfl_xor(a1.w, 16);
      a2.x += __shfl_xor(a2.x, 16); a2.y += __shfl_xor(a2.y, 16); a2.z += __shfl_xor(a2.z, 16); a2.w += __shfl_xor(a2.w, 16);
      a3.x += __shfl_xor(a3.x, 16); a3.y += __shfl_xor(a3.y, 16); a3.z += __shfl_xor(a3.z, 16); a3.w += __shfl_xor(a3.w, 16);
      if (grp == 0){
        float4 fs = fp8x4_f4(*(const unsigned int*)(H8 + ((size_t)node << 6) + c0b));   // self term
        a0 = f4fma(a0, wself.x, fs);
        a1 = f4fma(a1, wself.y, fs);
        a2 = f4fma(a2, wself.z, fs);
        a3 = f4fma(a3, wself.w, fs);
        a0 = f4scale(a0, 1.f/(z4.x + 1e-16f));
        a1 = f4scale(a1, 1.f/(z4.y + 1e-16f));
        a2 = f4scale(a2, 1.f/(z4.z + 1e-16f));
        a3 = f4scale(a3, 1.f/(z4.w + 1e-16f));
        // Y row -> LDS (head-major, bf16, same rounding as before)
        unsigned short* yp = &ytile[lrow32][sub << 2];
        *(ushort4*)(yp)       = f2bf4(a0);
        *(ushort4*)(yp + 64)  = f2bf4(a1);
        *(ushort4*)(yp + 128) = f2bf4(a2);
        *(ushort4*)(yp + 192) = f2bf4(a3);
      }
    } else if (grp == 0){
      ushort4 z = make_ushort4(0,0,0,0);
      unsigned short* yp = &ytile[lrow32][sub << 2];
      *(ushort4*)(yp)       = z;
      *(ushort4*)(yp + 64)  = z;
      *(ushort4*)(yp + 128) = z;
      *(ushort4*)(yp + 192) = z;
    }
  }
  __syncthreads();      // ytile complete; wl/sl dead from here (gtile aliases them)
  // ---- GEMM phase over this block's 32 node-rows (two full 16-row MFMA tiles) ----
  int wv = tid >> 6, l = tid & 63;
  int lrow = l & 15;
  int lk = (l >> 4) << 3;
  int rbase4 = (l >> 4) << 2;         // 0,4,8,12
  // stage-A: G = relu(ytile@Wg + bg); wave wv owns head wv (col-chunks cc = wv*4..wv*4+3)
  bf16x8 afA[2][2];                   // [tile][kb]
  #pragma unroll
  for (int t = 0; t < 2; ++t){
    afA[t][0] = *(const bf16x8*)&ytile[t*16 + lrow][wv*64 + lk];
    afA[t][1] = *(const bf16x8*)&ytile[t*16 + lrow][wv*64 + 32 + lk];
  }
  #pragma unroll
  for (int q = 0; q < 4; ++q){
    int cc = wv*4 + q;
    bf16x8 b0 = *(const bf16x8*)&WT1[((size_t)((0*16 + cc)*64 + l))*8];
    bf16x8 b1 = *(const bf16x8*)&WT1[((size_t)((1*16 + cc)*64 + l))*8];
    int c = cc*16 + lrow;
    float bv = bg[c];
    #pragma unroll
    for (int t = 0; t < 2; ++t){
      f32x4 acc = {0.f, 0.f, 0.f, 0.f};
      acc = __builtin_amdgcn_mfma_f32_16x16x32_bf16(afA[t][0], b0, acc, 0, 0, 0);
      acc = __builtin_amdgcn_mfma_f32_16x16x32_bf16(afA[t][1], b1, acc, 0, 0, 0);
      #pragma unroll
      for (int r = 0; r < 4; ++r)
        gtile[(t*16 + rbase4 + r)*264 + c] = f2bf(fmaxf(acc[r] + bv, 0.f));
    }
  }
  __syncthreads();      // gtile complete (cross-wave columns)
  // stage-B: [P8|R] = G @ [Wl|Wr]; wave wv owns cc = wv*2, wv*2+1; B-frags shared across tiles
  bf16x8 afb[2][8];
  #pragma unroll
  for (int t = 0; t < 2; ++t)
    #pragma unroll
    for (int kb = 0; kb < 8; ++kb)
      afb[t][kb] = *(const bf16x8*)&gtile[(t*16 + lrow)*264 + kb*32 + lk];
  #pragma unroll
  for (int q = 0; q < 2; ++q){
    int cc = wv*2 + q;
    f32x4 acc0 = {0.f, 0.f, 0.f, 0.f};
    f32x4 acc1 = {0.f, 0.f, 0.f, 0.f};
    #pragma unroll
    for (int kb = 0; kb < 8; ++kb){
      bf16x8 b = *(const bf16x8*)&WT2[((size_t)((kb*8 + cc)*64 + l))*8];
      acc0 = __builtin_amdgcn_mfma_f32_16x16x32_bf16(afb[0][kb], b, acc0, 0, 0, 0);
      acc1 = __builtin_amdgcn_mfma_f32_16x16x32_bf16(afb[1][kb], b, acc1, 0, 0, 0);
    }
    int c = cc*16 + lrow;
    #pragma unroll
    for (int t = 0; t < 2; ++t){
      const f32x4& acc = t ? acc1 : acc0;
      #pragma unroll
      for (int r = 0; r < 4; ++r){
        int nd = blockIdx.x*32 + t*16 + rbase4 + r;
        if (nd < n){
          float v = acc[r];
          if (c < 64) P8[(size_t)nd*64 + c] = f2fp8(v);
          else        R[(size_t)nd*64 + (c - 64)] = f2bf(v);
        }
      }
    }
  }
}

// ---------- SAGE aggregation + fused edge-MLP GEMM epilogue ----------
// Gather loop 4-deep (4 rows in flight); chain order preserved. W1 frags from L2-resident WT3.
__global__ __launch_bounds__(256) void k_sage(const unsigned char* __restrict__ P8, const unsigned short* __restrict__ R,
                                              const float* __restrict__ b, const int* __restrict__ offs,
                                              const int* __restrict__ csr, const unsigned short* __restrict__ WT3,
                                              unsigned char* __restrict__ T2, int n){
  __shared__ unsigned short stile[16][72];     // 16 S rows bf16, pad 72 (144 B stride)
  int tid = threadIdx.x;
  int wv = tid >> 6, l = tid & 63;
  int base = blockIdx.x*16;
  int lrow16 = (wv << 2) + (l >> 4);           // block-local row 0..15
  int node = base + lrow16;
  int l15 = l & 15;
  int grp = l15 >> 3, sub = l15 & 7;
  bool ok = node < n;
  int beg = 0, end = 0;
  if (ok){ beg = offs[node]; end = offs[node+1]; }
  float4 aL0 = f4s(0.f), aH0 = f4s(0.f), aL1 = f4s(0.f), aH1 = f4s(0.f);
  int i = beg + grp;
  for (; i + 6 < end; i += 8){
    int s0 = csr[i], s1 = csr[i+2], s2 = csr[i+4], s3 = csr[i+6];
    uint2 u0 = *(const uint2*)(P8 + (size_t)s0*64 + (sub<<3));
    uint2 u1 = *(const uint2*)(P8 + (size_t)s1*64 + (sub<<3));
    uint2 u2 = *(const uint2*)(P8 + (size_t)s2*64 + (sub<<3));
    uint2 u3 = *(const uint2*)(P8 + (size_t)s3*64 + (sub<<3));
    aL0 = f4add(aL0, fp8x4_f4(u0.x)); aH0 = f4add(aH0, fp8x4_f4(u0.y));
    aL1 = f4add(aL1, fp8x4_f4(u1.x)); aH1 = f4add(aH1, fp8x4_f4(u1.y));
    aL0 = f4add(aL0, fp8x4_f4(u2.x)); aH0 = f4add(aH0, fp8x4_f4(u2.y));
    aL1 = f4add(aL1, fp8x4_f4(u3.x)); aH1 = f4add(aH1, fp8x4_f4(u3.y));
  }
  for (; i + 2 < end; i += 4){
    int s0 = csr[i], s1 = csr[i+2];
    uint2 u0 = *(const uint2*)(P8 + (size_t)s0*64 + (sub<<3));
    uint2 u1 = *(const uint2*)(P8 + (size_t)s1*64 + (sub<<3));
    aL0 = f4add(aL0, fp8x4_f4(u0.x)); aH0 = f4add(aH0, fp8x4_f4(u0.y));
    aL1 = f4add(aL1, fp8x4_f4(u1.x)); aH1 = f4add(aH1, fp8x4_f4(u1.y));
  }
  if (i < end){
    int s0 = csr[i];
    uint2 u0 = *(const uint2*)(P8 + (size_t)s0*64 + (sub<<3));
    aL0 = f4add(aL0, fp8x4_f4(u0.x)); aH0 = f4add(aH0, fp8x4_f4(u0.y));
  }
  float4 aL = f4add(aL0, aL1), aH = f4add(aH0, aH1);
  red2(aL, aH);
  float4 r0 = f4s(0.f), r1 = f4s(0.f);
  if (ok){
    float minv = 1.f / fmaxf((float)(end - beg), 1.f);
    uint4 ur = *(const uint4*)(R + (size_t)node*64 + (sub<<3));
    float4 b0 = *(const float4*)(b + (sub<<3));
    float4 b1 = *(const float4*)(b + (sub<<3) + 4);
    r0 = f4relu(f4add(f4fma(b0, minv, aL), bfu2f4_lo(ur)));
    r1 = f4relu(f4add(f4fma(b1, minv, aH), bfu2f4_hi(ur)));
  }
  if (grp == 0) *(u16x8*)&stile[lrow16][sub << 3] = f2bf8(r0, r1);
  __syncthreads();
  // MFMA epilogue: 16 rows x 128 cols, K=64; waves split the 8 col-chunks (2 each)
  int lrow = l & 15, lk = (l >> 4) << 3;
  bf16x8 af0 = *(const bf16x8*)&stile[lrow][lk];
  bf16x8 af1 = *(const bf16x8*)&stile[lrow][32 + lk];
  int rbase = (l >> 4) << 2;
  #pragma unroll
  for (int q = 0; q < 2; ++q){
    int cc = wv*2 + q;
    f32x4 acc = {0.f, 0.f, 0.f, 0.f};
    acc = __builtin_amdgcn_mfma_f32_16x16x32_bf16(af0, *(const bf16x8*)&WT3[((size_t)((0*8 + cc)*64 + l))*8], acc, 0, 0, 0);
    acc = __builtin_amdgcn_mfma_f32_16x16x32_bf16(af1, *(const bf16x8*)&WT3[((size_t)((1*8 + cc)*64 + l))*8], acc, 0, 0, 0);
    int c = cc*16 + lrow;
    #pragma unroll
    for (int r = 0; r < 4; ++r){
      int nd = base + rbase + r;
      if (nd < n) T2[(size_t)nd*128 + c] = f2fp8(acc[r]);
    }
  }
}

// ---------- edge MLP, edge-order: 8 lanes/edge; T2 = [U|V] fp8 rows of 128 B ----------
__global__ __launch_bounds__(256) void k_mlp(const unsigned char* __restrict__ T2,
                                             const float* __restrict__ b1, const float* __restrict__ W2,
                                             const float* __restrict__ b2, const int* __restrict__ src,
                                             const int* __restrict__ dst, float* __restrict__ out, int E){
  int t = threadIdx.x;
  int e = blockIdx.x*32 + (t >> 3);
  if (e >= E) return;
  int sub = t & 7;
  int s = src[e], d = dst[e];
  uint2 uu = *(const uint2*)(T2 + (size_t)s*128 + (sub<<3));        // 8 fp8 of U[s]
  uint2 vv = *(const uint2*)(T2 + (size_t)d*128 + 64 + (sub<<3));   // 8 fp8 of V[d]
  float4 u0 = fp8x4_f4(uu.x), u1 = fp8x4_f4(uu.y);
  float4 v0 = fp8x4_f4(vv.x), v1 = fp8x4_f4(vv.y);
  float4 bb0 = *(const float4*)(b1 + (sub<<3));
  float4 bb1 = *(const float4*)(b1 + (sub<<3) + 4);
  float4 w0 = *(const float4*)(W2 + (sub<<3));
  float4 w1 = *(const float4*)(W2 + (sub<<3) + 4);
  float4 ta = f4relu(f4add(f4add(u0, v0), bb0));
  float4 tb = f4relu(f4add(f4add(u1, v1), bb1));
  float p = ta.x*w0.x + ta.y*w0.y + ta.z*w0.z + ta.w*w0.w
          + tb.x*w1.x + tb.y*w1.y + tb.z*w1.z + tb.w*w1.w;
  p += __shfl_xor(p, 1);
  p += __shfl_xor(p, 2);
  p += __shfl_xor(p, 4);
  if (sub == 0) out[e] = 1.f / (1.f + __expf(-(p + b2[0])));
}

extern "C" void kernel_launch(void* const* d_in, const int* in_sizes, int n_in,
                              void* d_out, int out_size, void* d_ws, size_t ws_size,
                              hipStream_t stream){
  const float* x     = (const float*)d_in[0];
  const int*   eidx  = (const int*)  d_in[1];
  const float* W_gcn = (const float*)d_in[2];
  const float* b_gcn = (const float*)d_in[3];
  const float* W_gat = (const float*)d_in[4];
  const float* att_s = (const float*)d_in[5];
  const float* att_d = (const float*)d_in[6];
  const float* b_gat = (const float*)d_in[7];
  const float* W_sl  = (const float*)d_in[8];
  const float* b_sg  = (const float*)d_in[9];
  const float* W_sr  = (const float*)d_in[10];
  const float* W1    = (const float*)d_in[11];
  const float* b1    = (const float*)d_in[12];
  const float* W2    = (const float*)d_in[13];
  const float* b2    = (const float*)d_in[14];
  float* out = (float*)d_out;

  const int N = in_sizes[0] / 128;
  const int E = in_sizes[1] / 2;
  const int* src = eidx;
  const int* dst = eidx + E;

  // ---- workspace layout: f32, then bf16, then fp8, then int ----
  float* ws   = (float*)d_ws;
  float* dinv = ws;                        // N
  float* D    = dinv + (size_t)N;          // N*8  (a_s | a_d)
  float* Vs   = D + (size_t)N*8;           // 256
  float* Vd   = Vs + 256;                  // 256
  unsigned short* WT = (unsigned short*)(Vd + 256);        // 7168*8 bf16 weight frag tables (112 KB)
  unsigned short* R  = WT + (size_t)7168*8;// N*64  bf16 (SAGE root term, compact)
  unsigned char*  A8 = (unsigned char*)(R + (size_t)N*64); // N*64  fp8 (dinv * x @ W_gcn)
  unsigned char*  H8 = A8 + (size_t)N*64;  // N*64  fp8 (GCN out shadow)
  unsigned char*  P8 = H8 + (size_t)N*64;  // N*64  fp8 (SAGE neighbor term, compact)
  unsigned char*  T2 = P8 + (size_t)N*64;  // N*128 fp8 (U | V)
  int* cnt  = (int*)(T2 + (size_t)N*128);  // N
  int* excl = cnt + N;                     // N
  int* bsum = excl + N;                    // 256
  int* offs = bsum + 256;                  // N+1
  int* rank = offs + N + 1;                // E
  int* csr  = rank + E;                    // E

  const int nb = (N + 255) / 256;
  const int fb = (E + 255) / 256;
  const int gtiles = (N + 63) / 64;
  const int nwb = (N + 15) / 16;          // 4 nodes/wave kernels (16 nodes/block)

  // ---- CSR build (+ packed independent work: WT frag tables, Vs/Vd basis, GCN GEMM) ----
  hipMemsetAsync(cnt, 0, (size_t)N*sizeof(int), stream);
  k_rankw <<<fb + 28, 256, 0, stream>>>(dst, cnt, rank, E, fb, W_gat, W_sl, W_sr,
                                        W1, W1 + 64*64, WT);
  k_scan1v<<<nb + 1, 256, 0, stream>>>(cnt, excl, bsum, N, nb, W_gat, att_s, att_d, Vs, Vd);
  k_scan3b<<<nb, 256, 0, stream>>>(cnt, excl, bsum, offs, dinv, N, E, nb);
  k_fillg <<<fb + gtiles, 256, 0, stream>>>(src, dst, offs, rank, csr, E, fb,
                                            x, W_gcn, A8, N, dinv);

  // ---- GCN aggregation: H8 = relu(...); D = GAT logits (fused epilogue) ----
  k_gcn <<<nwb, 256, 0, stream>>>(A8, dinv, b_gcn, offs, csr, Vs, Vd, H8, D, N);

  // ---- GAT softmax + aggregation + GAT-GEMM + SAGE-GEMM fused (32 nodes/block): -> [P8 | R] ----
  k_gat2f<<<(N+31)/32, 256, 0, stream>>>(D, H8, offs, csr, WT, b_gat, R, P8, N);

  // ---- SAGE + edge GEMM fused: S = relu(mean(P8[src]) + b + R); T2 = fp8(S @ WT3) ----
  k_sage<<<nwb, 256, 0, stream>>>(P8, R, b_sg, offs, csr, WT + (size_t)6144*8, T2, N);

  // ---- edge MLP: edge-order eval, coalesced out ----
  k_mlp <<<(E+31)/32, 256, 0, stream>>>(T2, b1, W2, b2, src, dst, out, E);
}